// Round 4
// baseline (353.107 us; speedup 1.0000x reference)
//
#include <hip/hip_runtime.h>
#include <hip/hip_bf16.h>

#define NB 4
#define CH 256
#define HWT 3600
#define KNN 8
#define ITERS 2
#define POSB 8
#define MPAD 3712

#define S_SEG 30
#define TILE 60
#define TPS 2      // S_SEG*TPS*TILE == HWT
#define RB 5
#define RPT 3      // RB*256*RPT = 3840 >= HWT

typedef __attribute__((ext_vector_type(8))) __bf16 bf16x8;
typedef __attribute__((ext_vector_type(4))) float f32x4;

__device__ inline float med3f(float a, float b, float c) {
    return __builtin_amdgcn_fmed3f(a, b, c);
}

// ---------------- kNN ----------------
__global__ void knn_prep(const float* __restrict__ rgb, const float* __restrict__ ir,
                         float* __restrict__ xpack) {
    int t = blockIdx.x * blockDim.x + threadIdx.x;
    if (t >= 2 * NB * HWT) return;
    int nm = t / HWT, j = t - nm * HWT;
    int mod = nm / NB, n = nm - mod * NB;
    const float* x = (mod == 0 ? rgb : ir) + (size_t)n * 5 * HWT;
    float v[5], q = 0.f;
#pragma unroll
    for (int d = 0; d < 5; ++d) { v[d] = x[d * HWT + j]; q = fmaf(v[d], v[d], q); }
    float* o = xpack + (size_t)t * 8;
#pragma unroll
    for (int d = 0; d < 5; ++d) o[d] = v[d];
    o[5] = q; o[6] = 0.f; o[7] = 0.f;
}

__global__ __launch_bounds__(256) void knn_main(const float* __restrict__ xpack,
                                                unsigned* __restrict__ partial) {
    int seg = blockIdx.x, rb = blockIdx.y, nm = blockIdx.z;
    int t = threadIdx.x;
    int row0 = rb * (256 * RPT) + t * RPT;
    const float* xp = xpack + (size_t)nm * HWT * 8;
    __shared__ float4 xs[TILE * 2];

    float xi[RPT][5], qi1[RPT];
#pragma unroll
    for (int r = 0; r < RPT; ++r) {
        int row = row0 + r;
        int rr = (row < HWT) ? row : (HWT - 1);
        float4 a = ((const float4*)xp)[rr * 2];
        float4 b = ((const float4*)xp)[rr * 2 + 1];
        xi[r][0] = a.x; xi[r][1] = a.y; xi[r][2] = a.z; xi[r][3] = a.w; xi[r][4] = b.x;
        qi1[r] = b.y + 1.0f;
    }
    const float BIG = __uint_as_float(0x7F000000u);
    float best[RPT][8];
#pragma unroll
    for (int r = 0; r < RPT; ++r)
#pragma unroll
        for (int i = 0; i < 8; ++i) best[r][i] = BIG;

    int jbase = seg * (TPS * TILE);
    for (int tl = 0; tl < TPS; ++tl) {
        int j0 = jbase + tl * TILE;
        __syncthreads();
        if (t < TILE * 2) xs[t] = ((const float4*)xp)[j0 * 2 + t];
        __syncthreads();
        for (int jj = 0; jj < TILE; ++jj) {
            float4 a = xs[jj * 2];
            float4 b = xs[jj * 2 + 1];
            unsigned jg = (unsigned)(j0 + jj);
#pragma unroll
            for (int r = 0; r < RPT; ++r) {
                float dot = a.x * xi[r][0];
                dot = fmaf(a.y, xi[r][1], dot);
                dot = fmaf(a.z, xi[r][2], dot);
                dot = fmaf(a.w, xi[r][3], dot);
                dot = fmaf(b.x, xi[r][4], dot);
                float d2 = fmaf(-2.0f, dot, b.y + qi1[r]);
                unsigned kb = (__float_as_uint(d2) & 0xFFFFF000u) | jg;
                float kf = __uint_as_float(kb);
                best[r][7] = med3f(best[r][6], best[r][7], kf);
                best[r][6] = med3f(best[r][5], best[r][6], kf);
                best[r][5] = med3f(best[r][4], best[r][5], kf);
                best[r][4] = med3f(best[r][3], best[r][4], kf);
                best[r][3] = med3f(best[r][2], best[r][3], kf);
                best[r][2] = med3f(best[r][1], best[r][2], kf);
                best[r][1] = med3f(best[r][0], best[r][1], kf);
                best[r][0] = fminf(best[r][0], kf);
            }
        }
    }
#pragma unroll
    for (int r = 0; r < RPT; ++r) {
        int row = row0 + r;
        if (row < HWT) {
            unsigned* o = partial + (((size_t)nm * S_SEG + seg) * HWT + row) * 8;
            uint4 lo = { __float_as_uint(best[r][0]), __float_as_uint(best[r][1]),
                         __float_as_uint(best[r][2]), __float_as_uint(best[r][3]) };
            uint4 hi = { __float_as_uint(best[r][4]), __float_as_uint(best[r][5]),
                         __float_as_uint(best[r][6]), __float_as_uint(best[r][7]) };
            ((uint4*)o)[0] = lo;
            ((uint4*)o)[1] = hi;
        }
    }
}

// 2 lanes per row: each merges 15 segments, then shuffle-exchange final merge
__global__ __launch_bounds__(256) void knn_merge(const unsigned* __restrict__ partial,
                                                 int* __restrict__ knn_rgb,
                                                 int* __restrict__ knn_ir) {
    int tid = blockIdx.x * blockDim.x + threadIdx.x;
    if (tid >= 2 * 2 * NB * HWT) return;
    int rid = tid >> 1, sub = tid & 1;
    int nm = rid / HWT, row = rid - nm * HWT;
    const float BIG = __uint_as_float(0x7F000000u);
    float best[8];
#pragma unroll
    for (int i = 0; i < 8; ++i) best[i] = BIG;
    for (int s = sub; s < S_SEG; s += 2) {
        const unsigned* p = partial + (((size_t)nm * S_SEG + s) * HWT + row) * 8;
#pragma unroll
        for (int w = 0; w < 2; ++w) {
            uint4 v = ((const uint4*)p)[w];
            unsigned vv[4] = { v.x, v.y, v.z, v.w };
#pragma unroll
            for (int e = 0; e < 4; ++e) {
                float kf = __uint_as_float(vv[e]);
                best[7] = med3f(best[6], best[7], kf);
                best[6] = med3f(best[5], best[6], kf);
                best[5] = med3f(best[4], best[5], kf);
                best[4] = med3f(best[3], best[4], kf);
                best[3] = med3f(best[2], best[3], kf);
                best[2] = med3f(best[1], best[2], kf);
                best[1] = med3f(best[0], best[1], kf);
                best[0] = fminf(best[0], kf);
            }
        }
    }
    float other[8];
#pragma unroll
    for (int i = 0; i < 8; ++i) other[i] = __shfl_xor(best[i], 1);
#pragma unroll
    for (int i = 0; i < 8; ++i) {
        float kf = other[i];
        best[7] = med3f(best[6], best[7], kf);
        best[6] = med3f(best[5], best[6], kf);
        best[5] = med3f(best[4], best[5], kf);
        best[4] = med3f(best[3], best[4], kf);
        best[3] = med3f(best[2], best[3], kf);
        best[2] = med3f(best[1], best[2], kf);
        best[1] = med3f(best[0], best[1], kf);
        best[0] = fminf(best[0], kf);
    }
    if (sub == 0) {
        int mod = nm / NB, n = nm - mod * NB;
        int* o = (mod == 0 ? knn_rgb : knn_ir) + ((size_t)n * HWT + row) * KNN;
#pragma unroll
        for (int i = 0; i < 8; ++i) o[i] = (int)(__float_as_uint(best[i]) & 0xFFFu);
    }
}

// ---------------- weight prep ----------------
__global__ void init_kernel(const float* __restrict__ Wg_rgb, const float* __restrict__ Wg_ir,
                            float* __restrict__ Wcomb, float* __restrict__ g) {
    int t = blockIdx.x * blockDim.x + threadIdx.x;
    if (t < 1024 * 256) {
        int o = t >> 8, j = t & 255;
        float v;
        if (o < 256)      v = Wg_rgb[o * 512 + j] + Wg_rgb[o * 512 + 256 + j];
        else if (o < 512) v = Wg_rgb[(o - 256) * 512 + 256 + j];
        else if (o < 768) v = Wg_ir[(o - 512) * 512 + j] + Wg_ir[(o - 512) * 512 + 256 + j];
        else              v = Wg_ir[(o - 768) * 512 + 256 + j];
        Wcomb[t] = v;
    }
    if (t < NB * CH) g[t] = 1.0f;
}

__global__ __launch_bounds__(256) void scale_w(const float* __restrict__ Wcomb,
                                               const float* __restrict__ g,
                                               __hip_bfloat16* __restrict__ Wbf) {
    int n = blockIdx.y;
    int gid = blockIdx.x * 256 + threadIdx.x;
    int o = gid >> 5;
    int kb = (gid & 31) * 8;
    const float* w = Wcomb + o * 256 + kb;
    const float* gp = g + n * CH + kb;
    union { uint4 u; __hip_bfloat16 h[8]; } pk;
#pragma unroll
    for (int i = 0; i < 8; ++i) pk.h[i] = __float2bfloat16(w[i] * gp[i]);
    *(uint4*)(Wbf + ((size_t)n * 1024 + o) * CH + kb) = pk.u;
}

__global__ __launch_bounds__(256) void convert_a(const float* __restrict__ cnn,
                                                 __hip_bfloat16* __restrict__ Abf) {
    __shared__ float st[64][65];
    int n = blockIdx.z, k0 = blockIdx.y * 64, m0 = blockIdx.x * 64;
    int t = threadIdx.x;
    const float* src = cnn + (size_t)n * CH * HWT;
#pragma unroll
    for (int r = 0; r < 4; ++r) {
        int kl = r * 16 + (t >> 4);
        int ms = (t & 15) * 4;
        float4 v = {0.f, 0.f, 0.f, 0.f};
        if (m0 + ms < HWT) v = *(const float4*)(src + (size_t)(k0 + kl) * HWT + m0 + ms);
        st[ms + 0][kl] = v.x; st[ms + 1][kl] = v.y;
        st[ms + 2][kl] = v.z; st[ms + 3][kl] = v.w;
    }
    __syncthreads();
    int m = t >> 2, kg = (t & 3) * 16;
    union { uint4 u[2]; __hip_bfloat16 h[16]; } pk;
#pragma unroll
    for (int i = 0; i < 16; ++i) pk.h[i] = __float2bfloat16(st[m][kg + i]);
    __hip_bfloat16* dst = Abf + ((size_t)n * MPAD + m0 + m) * CH + k0 + kg;
    ((uint4*)dst)[0] = pk.u[0];
    ((uint4*)dst)[1] = pk.u[1];
}

// ---------------- MFMA GEMM with K-tile register prefetch ----------------
__global__ __launch_bounds__(256) void gemm_mfma(const __hip_bfloat16* __restrict__ Abf,
                                                 const __hip_bfloat16* __restrict__ Wbf,
                                                 __hip_bfloat16* __restrict__ Yall) {
    __shared__ char sA[16384];
    __shared__ char sB[16384];
    int n = blockIdx.z;
    int m0 = blockIdx.x * 128;
    int o0 = blockIdx.y * 128;
    int t = threadIdx.x;
    int lane = t & 63, wid = t >> 6;
    int wm = wid >> 1, wo = wid & 1;

    const __hip_bfloat16* Ab = Abf + (size_t)n * MPAD * CH;
    const __hip_bfloat16* Wb = Wbf + (size_t)n * 1024 * CH;

    f32x4 acc[4][4] = {};

    int srow = t >> 3;
    int sslot = t & 7;
    int swz = (sslot ^ (srow & 7)) << 4;
    int fr = lane & 15;
    int kg = lane >> 4;
    int p = lane & 7;

    uint4 av[4], bv[4];
    auto load_tile = [&](int ks) {
#pragma unroll
        for (int r = 0; r < 4; ++r) {
            int row = srow + 32 * r;
            av[r] = *(const uint4*)(Ab + ((size_t)(m0 + row)) * CH + ks * 64 + sslot * 8);
            bv[r] = *(const uint4*)(Wb + ((size_t)(o0 + row)) * CH + ks * 64 + sslot * 8);
        }
    };
    load_tile(0);

    for (int ks = 0; ks < 4; ++ks) {
        __syncthreads();
#pragma unroll
        for (int r = 0; r < 4; ++r) {
            int row = srow + 32 * r;
            *(uint4*)(sA + row * 128 + swz) = av[r];
            *(uint4*)(sB + row * 128 + swz) = bv[r];
        }
        __syncthreads();
        if (ks < 3) load_tile(ks + 1);
#pragma unroll
        for (int kk = 0; kk < 2; ++kk) {
            bf16x8 hf[4], wf[4];
            int slot = kk * 4 + kg;
            int inrow = (slot ^ p) << 4;
#pragma unroll
            for (int f = 0; f < 4; ++f) {
                hf[f] = *(const bf16x8*)(sA + (wm * 64 + f * 16 + fr) * 128 + inrow);
                wf[f] = *(const bf16x8*)(sB + (wo * 64 + f * 16 + fr) * 128 + inrow);
            }
#pragma unroll
            for (int fa = 0; fa < 4; ++fa)
#pragma unroll
                for (int fb = 0; fb < 4; ++fb)
                    acc[fa][fb] = __builtin_amdgcn_mfma_f32_16x16x32_bf16(
                        wf[fa], hf[fb], acc[fa][fb], 0, 0, 0);
        }
    }

    __hip_bfloat16* Y = Yall + (size_t)n * HWT * 1024;
#pragma unroll
    for (int fa = 0; fa < 4; ++fa)
#pragma unroll
        for (int fb = 0; fb < 4; ++fb) {
            int m = m0 + wm * 64 + fb * 16 + fr;
            int o = o0 + wo * 64 + fa * 16 + kg * 4;
            if (m < HWT) {
                f32x4 v = acc[fa][fb];
                union { ushort4 u; __hip_bfloat16 h[4]; } pk;
                pk.h[0] = __float2bfloat16(v.x);
                pk.h[1] = __float2bfloat16(v.y);
                pk.h[2] = __float2bfloat16(v.z);
                pk.h[3] = __float2bfloat16(v.w);
                *(ushort4*)(Y + (size_t)m * 1024 + o) = pk.u;
            }
        }
}

// ---------------- gather / SE / final ----------------
__global__ void zero_cc(float* __restrict__ ccsum) {
    int t = blockIdx.x * blockDim.x + threadIdx.x;
    if (t < NB * 512) ccsum[t] = 0.f;
}

// 2 channels per thread via u32 loads; threads 0-127: rgb, 128-255: ir
__global__ __launch_bounds__(256) void gather_kernel(const __hip_bfloat16* __restrict__ Yall,
                                                     const int* __restrict__ knn_rgb,
                                                     const int* __restrict__ knn_ir,
                                                     const float* __restrict__ b_rgb,
                                                     const float* __restrict__ b_ir,
                                                     float* __restrict__ ccsum) {
    int n = blockIdx.y;
    int hwbase = blockIdx.x * POSB;
    int t = threadIdx.x;
    int half = t >> 7;
    int cp = (t & 127) << 1;
    __shared__ int sidx[POSB][2][KNN];
    if (t < POSB * 2 * KNN) {
        int p = t >> 4, rem = t & 15;
        int hw = hwbase + p;
        int v;
        if (rem < 8) v = knn_rgb[((size_t)n * HWT + hw) * KNN + rem];
        else         v = knn_ir[((size_t)n * HWT + hw) * KNN + (rem - 8)];
        sidx[p][rem >> 3][rem & 7] = v;
    }
    __syncthreads();
    const float* bias = half ? b_ir : b_rgb;
    float b0 = bias[cp], b1 = bias[cp + 1];
    float acc0 = 0.f, acc1 = 0.f;
    const __hip_bfloat16* Y = Yall + (size_t)n * HWT * 1024;
    int offA = half * 512 + cp;
    int offB = half * 512 + 256 + cp;
    for (int p = 0; p < POSB; ++p) {
        float m0 = 0.f, m1 = 0.f;
#pragma unroll
        for (int k = 0; k < KNN; ++k) {
            int jA = sidx[p][half][k];
            int jB = sidx[p][half ^ 1][k];
            unsigned u1 = *(const unsigned*)(Y + (size_t)jA * 1024 + offA);
            unsigned u2 = *(const unsigned*)(Y + (size_t)jB * 1024 + offB);
            float a0 = __uint_as_float(u1 << 16);
            float a1 = __uint_as_float(u1 & 0xFFFF0000u);
            float c0 = __uint_as_float(u2 << 16);
            float c1 = __uint_as_float(u2 & 0xFFFF0000u);
            m0 = fmaxf(m0, a0 - c0 + b0);
            m1 = fmaxf(m1, a1 - c1 + b1);
        }
        acc0 += m0;
        acc1 += m1;
    }
    atomicAdd(&ccsum[n * 512 + half * 256 + cp], acc0);
    atomicAdd(&ccsum[n * 512 + half * 256 + cp + 1], acc1);
}

__global__ __launch_bounds__(256) void se_kernel(const float* __restrict__ ccsum,
                                                 const float* __restrict__ W1,
                                                 const float* __restrict__ b1,
                                                 const float* __restrict__ W2,
                                                 const float* __restrict__ b2,
                                                 float* __restrict__ g) {
    int n = blockIdx.x;
    int t = threadIdx.x;
    __shared__ float hid[16];
    __shared__ float cc[512];
    cc[t] = ccsum[n * 512 + t] * (1.0f / HWT);
    cc[256 + t] = ccsum[n * 512 + 256 + t] * (1.0f / HWT);
    __syncthreads();
    if (t < 16) {
        float s = b1[t];
        for (int j = 0; j < 512; ++j) s = fmaf(W1[t * 512 + j], cc[j], s);
        hid[t] = fmaxf(s, 0.f);
    }
    __syncthreads();
    float s = b2[t];
#pragma unroll
    for (int q = 0; q < 16; ++q) s = fmaf(W2[t * 16 + q], hid[q], s);
    float se = 1.0f / (1.0f + expf(-s));
    g[n * CH + t] *= se;
}

__global__ void final_kernel(const float* __restrict__ cnn, const float* __restrict__ g,
                             const float* __restrict__ gamma, float* __restrict__ out) {
    int t = blockIdx.x * blockDim.x + threadIdx.x;
    if (t >= NB * CH * HWT) return;
    int nc = t / HWT;
    float x = cnn[t];
    float s = gamma[0] * g[nc] + 1.0f;
    out[t] = fmaxf(s * x, 0.f);
}

extern "C" void kernel_launch(void* const* d_in, const int* in_sizes, int n_in,
                              void* d_out, int out_size, void* d_ws, size_t ws_size,
                              hipStream_t stream) {
    const float* cnn    = (const float*)d_in[0];
    const float* rgb    = (const float*)d_in[1];
    const float* ir     = (const float*)d_in[2];
    const float* Wg_rgb = (const float*)d_in[3];
    const float* bg_rgb = (const float*)d_in[4];
    const float* Wg_ir  = (const float*)d_in[5];
    const float* bg_ir  = (const float*)d_in[6];
    const float* Wse1   = (const float*)d_in[7];
    const float* bse1   = (const float*)d_in[8];
    const float* Wse2   = (const float*)d_in[9];
    const float* bse2   = (const float*)d_in[10];
    const float* gamma  = (const float*)d_in[11];
    float* out = (float*)d_out;

    char* ws = (char*)d_ws;
    size_t off = 0;
    float* xpack = (float*)(ws + off); off += (size_t)2 * NB * HWT * 8 * 4;
    int* knn_rgb = (int*)(ws + off); off += (size_t)NB * HWT * KNN * 4;
    int* knn_ir  = (int*)(ws + off); off += (size_t)NB * HWT * KNN * 4;
    float* Wcomb = (float*)(ws + off); off += (size_t)1024 * 256 * 4;
    __hip_bfloat16* Wbf = (__hip_bfloat16*)(ws + off); off += (size_t)NB * 1024 * CH * 2;
    __hip_bfloat16* Abf = (__hip_bfloat16*)(ws + off); off += (size_t)NB * MPAD * CH * 2;
    __hip_bfloat16* Yall = (__hip_bfloat16*)(ws + off);
    unsigned* partial = (unsigned*)Yall;  // aliases Y (27.6 MB < 29.5 MB), dead before gemm
    off += (size_t)NB * HWT * 1024 * 2;
    float* ccsum = (float*)(ws + off); off += (size_t)NB * 512 * 4;
    float* g     = (float*)(ws + off); off += (size_t)NB * CH * 4;

    knn_prep<<<(2 * NB * HWT + 255) / 256, 256, 0, stream>>>(rgb, ir, xpack);
    knn_main<<<dim3(S_SEG, RB, 2 * NB), 256, 0, stream>>>(xpack, partial);
    knn_merge<<<(4 * NB * HWT + 255) / 256, 256, 0, stream>>>(partial, knn_rgb, knn_ir);
    init_kernel<<<1024, 256, 0, stream>>>(Wg_rgb, Wg_ir, Wcomb, g);
    convert_a<<<dim3(MPAD / 64, 4, NB), 256, 0, stream>>>(cnn, Abf);

    for (int it = 0; it < ITERS; ++it) {
        scale_w<<<dim3(128, NB), 256, 0, stream>>>(Wcomb, g, Wbf);
        gemm_mfma<<<dim3(MPAD / 128, 8, NB), 256, 0, stream>>>(Abf, Wbf, Yall);
        zero_cc<<<8, 256, 0, stream>>>(ccsum);
        gather_kernel<<<dim3(HWT / POSB, NB), 256, 0, stream>>>(Yall, knn_rgb, knn_ir,
                                                                bg_rgb, bg_ir, ccsum);
        se_kernel<<<NB, 256, 0, stream>>>(ccsum, Wse1, bse1, Wse2, bse2, g);
    }
    final_kernel<<<(NB * CH * HWT + 255) / 256, 256, 0, stream>>>(cnn, g, gamma, out);
}

// Round 5
// 320.455 us; speedup vs baseline: 1.1019x; 1.1019x over previous
//
#include <hip/hip_runtime.h>
#include <hip/hip_bf16.h>

#define NB 4
#define CH 256
#define HWT 3600
#define KNN 8
#define ITERS 2
#define POSB 8
#define MPAD 3712

#define S_SEG 30
#define TILE 60
#define TPS 2      // S_SEG*TPS*TILE == HWT
#define RB 5
#define RPT 3      // RB*256*RPT = 3840 >= HWT

typedef __attribute__((ext_vector_type(8))) __bf16 bf16x8;
typedef __attribute__((ext_vector_type(4))) float f32x4;

__device__ inline float med3f(float a, float b, float c) {
    return __builtin_amdgcn_fmed3f(a, b, c);
}

// ---------------- kNN ----------------
__global__ void knn_prep(const float* __restrict__ rgb, const float* __restrict__ ir,
                         float* __restrict__ xpack) {
    int t = blockIdx.x * blockDim.x + threadIdx.x;
    if (t >= 2 * NB * HWT) return;
    int nm = t / HWT, j = t - nm * HWT;
    int mod = nm / NB, n = nm - mod * NB;
    const float* x = (mod == 0 ? rgb : ir) + (size_t)n * 5 * HWT;
    float v[5], q = 0.f;
#pragma unroll
    for (int d = 0; d < 5; ++d) { v[d] = x[d * HWT + j]; q = fmaf(v[d], v[d], q); }
    float* o = xpack + (size_t)t * 8;
#pragma unroll
    for (int d = 0; d < 5; ++d) o[d] = v[d];
    o[5] = q; o[6] = 0.f; o[7] = 0.f;
}

__global__ __launch_bounds__(256) void knn_main(const float* __restrict__ xpack,
                                                unsigned* __restrict__ partial) {
    int seg = blockIdx.x, rb = blockIdx.y, nm = blockIdx.z;
    int t = threadIdx.x;
    int row0 = rb * (256 * RPT) + t * RPT;
    const float* xp = xpack + (size_t)nm * HWT * 8;
    __shared__ float4 xs[TILE * 2];

    float xi[RPT][5], qi1[RPT];
#pragma unroll
    for (int r = 0; r < RPT; ++r) {
        int row = row0 + r;
        int rr = (row < HWT) ? row : (HWT - 1);
        float4 a = ((const float4*)xp)[rr * 2];
        float4 b = ((const float4*)xp)[rr * 2 + 1];
        xi[r][0] = a.x; xi[r][1] = a.y; xi[r][2] = a.z; xi[r][3] = a.w; xi[r][4] = b.x;
        qi1[r] = b.y + 1.0f;
    }
    const float BIG = __uint_as_float(0x7F000000u);
    float best[RPT][8];
#pragma unroll
    for (int r = 0; r < RPT; ++r)
#pragma unroll
        for (int i = 0; i < 8; ++i) best[r][i] = BIG;

    int jbase = seg * (TPS * TILE);
    for (int tl = 0; tl < TPS; ++tl) {
        int j0 = jbase + tl * TILE;
        __syncthreads();
        if (t < TILE * 2) xs[t] = ((const float4*)xp)[j0 * 2 + t];
        __syncthreads();
        for (int jj = 0; jj < TILE; ++jj) {
            float4 a = xs[jj * 2];
            float4 b = xs[jj * 2 + 1];
            unsigned jg = (unsigned)(j0 + jj);
#pragma unroll
            for (int r = 0; r < RPT; ++r) {
                float dot = a.x * xi[r][0];
                dot = fmaf(a.y, xi[r][1], dot);
                dot = fmaf(a.z, xi[r][2], dot);
                dot = fmaf(a.w, xi[r][3], dot);
                dot = fmaf(b.x, xi[r][4], dot);
                float d2 = fmaf(-2.0f, dot, b.y + qi1[r]);
                unsigned kb = (__float_as_uint(d2) & 0xFFFFF000u) | jg;
                float kf = __uint_as_float(kb);
                best[r][7] = med3f(best[r][6], best[r][7], kf);
                best[r][6] = med3f(best[r][5], best[r][6], kf);
                best[r][5] = med3f(best[r][4], best[r][5], kf);
                best[r][4] = med3f(best[r][3], best[r][4], kf);
                best[r][3] = med3f(best[r][2], best[r][3], kf);
                best[r][2] = med3f(best[r][1], best[r][2], kf);
                best[r][1] = med3f(best[r][0], best[r][1], kf);
                best[r][0] = fminf(best[r][0], kf);
            }
        }
    }
#pragma unroll
    for (int r = 0; r < RPT; ++r) {
        int row = row0 + r;
        if (row < HWT) {
            unsigned* o = partial + (((size_t)nm * S_SEG + seg) * HWT + row) * 8;
            uint4 lo = { __float_as_uint(best[r][0]), __float_as_uint(best[r][1]),
                         __float_as_uint(best[r][2]), __float_as_uint(best[r][3]) };
            uint4 hi = { __float_as_uint(best[r][4]), __float_as_uint(best[r][5]),
                         __float_as_uint(best[r][6]), __float_as_uint(best[r][7]) };
            ((uint4*)o)[0] = lo;
            ((uint4*)o)[1] = hi;
        }
    }
}

__global__ __launch_bounds__(256) void knn_merge(const unsigned* __restrict__ partial,
                                                 int* __restrict__ knn_rgb,
                                                 int* __restrict__ knn_ir) {
    int tid = blockIdx.x * blockDim.x + threadIdx.x;
    if (tid >= 2 * 2 * NB * HWT) return;
    int rid = tid >> 1, sub = tid & 1;
    int nm = rid / HWT, row = rid - nm * HWT;
    const float BIG = __uint_as_float(0x7F000000u);
    float best[8];
#pragma unroll
    for (int i = 0; i < 8; ++i) best[i] = BIG;
    for (int s = sub; s < S_SEG; s += 2) {
        const unsigned* p = partial + (((size_t)nm * S_SEG + s) * HWT + row) * 8;
#pragma unroll
        for (int w = 0; w < 2; ++w) {
            uint4 v = ((const uint4*)p)[w];
            unsigned vv[4] = { v.x, v.y, v.z, v.w };
#pragma unroll
            for (int e = 0; e < 4; ++e) {
                float kf = __uint_as_float(vv[e]);
                best[7] = med3f(best[6], best[7], kf);
                best[6] = med3f(best[5], best[6], kf);
                best[5] = med3f(best[4], best[5], kf);
                best[4] = med3f(best[3], best[4], kf);
                best[3] = med3f(best[2], best[3], kf);
                best[2] = med3f(best[1], best[2], kf);
                best[1] = med3f(best[0], best[1], kf);
                best[0] = fminf(best[0], kf);
            }
        }
    }
    float other[8];
#pragma unroll
    for (int i = 0; i < 8; ++i) other[i] = __shfl_xor(best[i], 1);
#pragma unroll
    for (int i = 0; i < 8; ++i) {
        float kf = other[i];
        best[7] = med3f(best[6], best[7], kf);
        best[6] = med3f(best[5], best[6], kf);
        best[5] = med3f(best[4], best[5], kf);
        best[4] = med3f(best[3], best[4], kf);
        best[3] = med3f(best[2], best[3], kf);
        best[2] = med3f(best[1], best[2], kf);
        best[1] = med3f(best[0], best[1], kf);
        best[0] = fminf(best[0], kf);
    }
    if (sub == 0) {
        int mod = nm / NB, n = nm - mod * NB;
        int* o = (mod == 0 ? knn_rgb : knn_ir) + ((size_t)n * HWT + row) * KNN;
#pragma unroll
        for (int i = 0; i < 8; ++i) o[i] = (int)(__float_as_uint(best[i]) & 0xFFFu);
    }
}

// ---------------- weight prep ----------------
__global__ void init_kernel(const float* __restrict__ Wg_rgb, const float* __restrict__ Wg_ir,
                            float* __restrict__ Wcomb, float* __restrict__ g) {
    int t = blockIdx.x * blockDim.x + threadIdx.x;
    if (t < 1024 * 256) {
        int o = t >> 8, j = t & 255;
        float v;
        if (o < 256)      v = Wg_rgb[o * 512 + j] + Wg_rgb[o * 512 + 256 + j];
        else if (o < 512) v = Wg_rgb[(o - 256) * 512 + 256 + j];
        else if (o < 768) v = Wg_ir[(o - 512) * 512 + j] + Wg_ir[(o - 512) * 512 + 256 + j];
        else              v = Wg_ir[(o - 768) * 512 + 256 + j];
        Wcomb[t] = v;
    }
    if (t < NB * CH) g[t] = 1.0f;
}

__global__ __launch_bounds__(256) void scale_w(const float* __restrict__ Wcomb,
                                               const float* __restrict__ g,
                                               __hip_bfloat16* __restrict__ Wbf) {
    int n = blockIdx.y;
    int gid = blockIdx.x * 256 + threadIdx.x;
    int o = gid >> 5;
    int kb = (gid & 31) * 8;
    const float* w = Wcomb + o * 256 + kb;
    const float* gp = g + n * CH + kb;
    union { uint4 u; __hip_bfloat16 h[8]; } pk;
#pragma unroll
    for (int i = 0; i < 8; ++i) pk.h[i] = __float2bfloat16(w[i] * gp[i]);
    *(uint4*)(Wbf + ((size_t)n * 1024 + o) * CH + kb) = pk.u;
}

__global__ __launch_bounds__(256) void convert_a(const float* __restrict__ cnn,
                                                 __hip_bfloat16* __restrict__ Abf) {
    __shared__ float st[64][65];
    int n = blockIdx.z, k0 = blockIdx.y * 64, m0 = blockIdx.x * 64;
    int t = threadIdx.x;
    const float* src = cnn + (size_t)n * CH * HWT;
#pragma unroll
    for (int r = 0; r < 4; ++r) {
        int kl = r * 16 + (t >> 4);
        int ms = (t & 15) * 4;
        float4 v = {0.f, 0.f, 0.f, 0.f};
        if (m0 + ms < HWT) v = *(const float4*)(src + (size_t)(k0 + kl) * HWT + m0 + ms);
        st[ms + 0][kl] = v.x; st[ms + 1][kl] = v.y;
        st[ms + 2][kl] = v.z; st[ms + 3][kl] = v.w;
    }
    __syncthreads();
    int m = t >> 2, kg = (t & 3) * 16;
    union { uint4 u[2]; __hip_bfloat16 h[16]; } pk;
#pragma unroll
    for (int i = 0; i < 16; ++i) pk.h[i] = __float2bfloat16(st[m][kg + i]);
    __hip_bfloat16* dst = Abf + ((size_t)n * MPAD + m0 + m) * CH + k0 + kg;
    ((uint4*)dst)[0] = pk.u[0];
    ((uint4*)dst)[1] = pk.u[1];
}

// ---------------- MFMA GEMM ----------------
// grid (232, NB); w = (lid%8)*29 + lid/8 -> XCD-contiguous m-tiles (A reuse in L2)
// epilogue: stage C-tile bf16 in LDS (XOR swizzle), stream full-line uint4 stores
__global__ __launch_bounds__(256) void gemm_mfma(const __hip_bfloat16* __restrict__ Abf,
                                                 const __hip_bfloat16* __restrict__ Wbf,
                                                 __hip_bfloat16* __restrict__ Yall) {
    __shared__ char smem[32768];
    char* sA = smem;
    char* sB = smem + 16384;
    int lid = blockIdx.x;
    int n = blockIdx.y;
    int w = (lid & 7) * 29 + (lid >> 3);
    int m0 = (w >> 3) * 128;
    int o0 = (w & 7) * 128;
    int t = threadIdx.x;
    int lane = t & 63, wid = t >> 6;
    int wm = wid >> 1, wo = wid & 1;

    const __hip_bfloat16* Ab = Abf + (size_t)n * MPAD * CH;
    const __hip_bfloat16* Wb = Wbf + (size_t)n * 1024 * CH;

    f32x4 acc[4][4] = {};

    int srow = t >> 3;
    int sslot = t & 7;
    int swz = (sslot ^ (srow & 7)) << 4;
    int fr = lane & 15;
    int kg = lane >> 4;
    int p = lane & 7;

    uint4 av[4], bv[4];
    auto load_tile = [&](int ks) {
#pragma unroll
        for (int r = 0; r < 4; ++r) {
            int row = srow + 32 * r;
            av[r] = *(const uint4*)(Ab + ((size_t)(m0 + row)) * CH + ks * 64 + sslot * 8);
            bv[r] = *(const uint4*)(Wb + ((size_t)(o0 + row)) * CH + ks * 64 + sslot * 8);
        }
    };
    load_tile(0);

    for (int ks = 0; ks < 4; ++ks) {
        __syncthreads();
#pragma unroll
        for (int r = 0; r < 4; ++r) {
            int row = srow + 32 * r;
            *(uint4*)(sA + row * 128 + swz) = av[r];
            *(uint4*)(sB + row * 128 + swz) = bv[r];
        }
        __syncthreads();
        if (ks < 3) load_tile(ks + 1);
#pragma unroll
        for (int kk = 0; kk < 2; ++kk) {
            bf16x8 hf[4], wf[4];
            int slot = kk * 4 + kg;
            int inrow = (slot ^ p) << 4;
#pragma unroll
            for (int f = 0; f < 4; ++f) {
                hf[f] = *(const bf16x8*)(sA + (wm * 64 + f * 16 + fr) * 128 + inrow);
                wf[f] = *(const bf16x8*)(sB + (wo * 64 + f * 16 + fr) * 128 + inrow);
            }
#pragma unroll
            for (int fa = 0; fa < 4; ++fa)
#pragma unroll
                for (int fb = 0; fb < 4; ++fb)
                    acc[fa][fb] = __builtin_amdgcn_mfma_f32_16x16x32_bf16(
                        wf[fa], hf[fb], acc[fa][fb], 0, 0, 0);
        }
    }

    // epilogue: acc -> LDS (bf16, swizzled) -> coalesced global
    __syncthreads();
#pragma unroll
    for (int fa = 0; fa < 4; ++fa)
#pragma unroll
        for (int fb = 0; fb < 4; ++fb) {
            int ml = wm * 64 + fb * 16 + fr;            // local m (D col = lane&15)
            int ob = (wo * 64 + fa * 16 + kg * 4) * 2;  // local o byte (D row)
            f32x4 v = acc[fa][fb];
            union { ushort4 u; __hip_bfloat16 h[4]; } pk;
            pk.h[0] = __float2bfloat16(v.x);
            pk.h[1] = __float2bfloat16(v.y);
            pk.h[2] = __float2bfloat16(v.z);
            pk.h[3] = __float2bfloat16(v.w);
            *(ushort4*)(smem + ml * 256 + (ob ^ ((ml & 7) << 4))) = pk.u;
        }
    __syncthreads();
    __hip_bfloat16* Y = Yall + (size_t)n * HWT * 1024;
    int m = t >> 1;
    int halfb = (t & 1) * 128;
    int grow = m0 + m;
    if (grow < HWT) {
        char* yr = (char*)(Y + (size_t)grow * 1024 + o0);
#pragma unroll
        for (int i = 0; i < 8; ++i) {
            int src = halfb + i * 16;
            int colb = src ^ ((m & 7) << 4);
            *(uint4*)(yr + colb) = *(const uint4*)(smem + m * 256 + src);
        }
    }
}

// ---------------- gather / SE / final ----------------
__global__ void zero_cc(float* __restrict__ ccsum) {
    int t = blockIdx.x * blockDim.x + threadIdx.x;
    if (t < NB * 512) ccsum[t] = 0.f;
}

__global__ __launch_bounds__(256) void gather_kernel(const __hip_bfloat16* __restrict__ Yall,
                                                     const int* __restrict__ knn_rgb,
                                                     const int* __restrict__ knn_ir,
                                                     const float* __restrict__ b_rgb,
                                                     const float* __restrict__ b_ir,
                                                     float* __restrict__ ccsum) {
    int n = blockIdx.y;
    int hwbase = blockIdx.x * POSB;
    int t = threadIdx.x;
    int half = t >> 7;
    int cp = (t & 127) << 1;
    __shared__ int sidx[POSB][2][KNN];
    if (t < POSB * 2 * KNN) {
        int p = t >> 4, rem = t & 15;
        int hw = hwbase + p;
        int v;
        if (rem < 8) v = knn_rgb[((size_t)n * HWT + hw) * KNN + rem];
        else         v = knn_ir[((size_t)n * HWT + hw) * KNN + (rem - 8)];
        sidx[p][rem >> 3][rem & 7] = v;
    }
    __syncthreads();
    const float* bias = half ? b_ir : b_rgb;
    float b0 = bias[cp], b1 = bias[cp + 1];
    float acc0 = 0.f, acc1 = 0.f;
    const __hip_bfloat16* Y = Yall + (size_t)n * HWT * 1024;
    int offA = half * 512 + cp;
    int offB = half * 512 + 256 + cp;
    for (int p = 0; p < POSB; ++p) {
        float m0 = 0.f, m1 = 0.f;
#pragma unroll
        for (int k = 0; k < KNN; ++k) {
            int jA = sidx[p][half][k];
            int jB = sidx[p][half ^ 1][k];
            unsigned u1 = *(const unsigned*)(Y + (size_t)jA * 1024 + offA);
            unsigned u2 = *(const unsigned*)(Y + (size_t)jB * 1024 + offB);
            float a0 = __uint_as_float(u1 << 16);
            float a1 = __uint_as_float(u1 & 0xFFFF0000u);
            float c0 = __uint_as_float(u2 << 16);
            float c1 = __uint_as_float(u2 & 0xFFFF0000u);
            m0 = fmaxf(m0, a0 - c0 + b0);
            m1 = fmaxf(m1, a1 - c1 + b1);
        }
        acc0 += m0;
        acc1 += m1;
    }
    atomicAdd(&ccsum[n * 512 + half * 256 + cp], acc0);
    atomicAdd(&ccsum[n * 512 + half * 256 + cp + 1], acc1);
}

__global__ __launch_bounds__(256) void se_kernel(const float* __restrict__ ccsum,
                                                 const float* __restrict__ W1,
                                                 const float* __restrict__ b1,
                                                 const float* __restrict__ W2,
                                                 const float* __restrict__ b2,
                                                 float* __restrict__ g) {
    int n = blockIdx.x;
    int t = threadIdx.x;
    __shared__ float hid[16];
    __shared__ float cc[512];
    cc[t] = ccsum[n * 512 + t] * (1.0f / HWT);
    cc[256 + t] = ccsum[n * 512 + 256 + t] * (1.0f / HWT);
    __syncthreads();
    if (t < 16) {
        float s = b1[t];
        for (int j = 0; j < 512; ++j) s = fmaf(W1[t * 512 + j], cc[j], s);
        hid[t] = fmaxf(s, 0.f);
    }
    __syncthreads();
    float s = b2[t];
#pragma unroll
    for (int q = 0; q < 16; ++q) s = fmaf(W2[t * 16 + q], hid[q], s);
    float se = 1.0f / (1.0f + expf(-s));
    g[n * CH + t] *= se;
}

__global__ void final_kernel(const float* __restrict__ cnn, const float* __restrict__ g,
                             const float* __restrict__ gamma, float* __restrict__ out) {
    int t = blockIdx.x * blockDim.x + threadIdx.x;
    if (t >= NB * CH * HWT / 4) return;
    int nc = (t * 4) / HWT;   // HWT % 4 == 0 -> uniform within the float4
    float4 x = ((const float4*)cnn)[t];
    float s = gamma[0] * g[nc] + 1.0f;
    float4 o;
    o.x = fmaxf(s * x.x, 0.f);
    o.y = fmaxf(s * x.y, 0.f);
    o.z = fmaxf(s * x.z, 0.f);
    o.w = fmaxf(s * x.w, 0.f);
    ((float4*)out)[t] = o;
}

extern "C" void kernel_launch(void* const* d_in, const int* in_sizes, int n_in,
                              void* d_out, int out_size, void* d_ws, size_t ws_size,
                              hipStream_t stream) {
    const float* cnn    = (const float*)d_in[0];
    const float* rgb    = (const float*)d_in[1];
    const float* ir     = (const float*)d_in[2];
    const float* Wg_rgb = (const float*)d_in[3];
    const float* bg_rgb = (const float*)d_in[4];
    const float* Wg_ir  = (const float*)d_in[5];
    const float* bg_ir  = (const float*)d_in[6];
    const float* Wse1   = (const float*)d_in[7];
    const float* bse1   = (const float*)d_in[8];
    const float* Wse2   = (const float*)d_in[9];
    const float* bse2   = (const float*)d_in[10];
    const float* gamma  = (const float*)d_in[11];
    float* out = (float*)d_out;

    char* ws = (char*)d_ws;
    size_t off = 0;
    float* xpack = (float*)(ws + off); off += (size_t)2 * NB * HWT * 8 * 4;
    int* knn_rgb = (int*)(ws + off); off += (size_t)NB * HWT * KNN * 4;
    int* knn_ir  = (int*)(ws + off); off += (size_t)NB * HWT * KNN * 4;
    float* Wcomb = (float*)(ws + off); off += (size_t)1024 * 256 * 4;
    __hip_bfloat16* Wbf = (__hip_bfloat16*)(ws + off); off += (size_t)NB * 1024 * CH * 2;
    __hip_bfloat16* Abf = (__hip_bfloat16*)(ws + off); off += (size_t)NB * MPAD * CH * 2;
    __hip_bfloat16* Yall = (__hip_bfloat16*)(ws + off);
    unsigned* partial = (unsigned*)Yall;  // aliases Y (27.6 MB < 29.5 MB), dead before gemm
    off += (size_t)NB * HWT * 1024 * 2;
    float* ccsum = (float*)(ws + off); off += (size_t)NB * 512 * 4;
    float* g     = (float*)(ws + off); off += (size_t)NB * CH * 4;

    knn_prep<<<(2 * NB * HWT + 255) / 256, 256, 0, stream>>>(rgb, ir, xpack);
    knn_main<<<dim3(S_SEG, RB, 2 * NB), 256, 0, stream>>>(xpack, partial);
    knn_merge<<<(4 * NB * HWT + 255) / 256, 256, 0, stream>>>(partial, knn_rgb, knn_ir);
    init_kernel<<<1024, 256, 0, stream>>>(Wg_rgb, Wg_ir, Wcomb, g);
    convert_a<<<dim3(MPAD / 64, 4, NB), 256, 0, stream>>>(cnn, Abf);

    for (int it = 0; it < ITERS; ++it) {
        scale_w<<<dim3(128, NB), 256, 0, stream>>>(Wcomb, g, Wbf);
        gemm_mfma<<<dim3(232, NB), 256, 0, stream>>>(Abf, Wbf, Yall);
        zero_cc<<<8, 256, 0, stream>>>(ccsum);
        gather_kernel<<<dim3(HWT / POSB, NB), 256, 0, stream>>>(Yall, knn_rgb, knn_ir,
                                                                bg_rgb, bg_ir, ccsum);
        se_kernel<<<NB, 256, 0, stream>>>(ccsum, Wse1, bse1, Wse2, bse2, g);
    }
    final_kernel<<<(NB * CH * HWT / 4 + 255) / 256, 256, 0, stream>>>(cnn, g, gamma, out);
}

// Round 6
// 247.862 us; speedup vs baseline: 1.4246x; 1.2929x over previous
//
#include <hip/hip_runtime.h>
#include <hip/hip_bf16.h>

#define NB 4
#define CH 256
#define HWT 3600
#define KNN 8
#define ITERS 2
#define POSB 16
#define MPAD 3712

#define S_SEG 30
#define TILE 60
#define TPS 2      // S_SEG*TPS*TILE == HWT
#define RB 5
#define RPT 3      // RB*256*RPT = 3840 >= HWT

typedef __attribute__((ext_vector_type(8))) __bf16 bf16x8;
typedef __attribute__((ext_vector_type(4))) float f32x4;

__device__ inline float med3f(float a, float b, float c) {
    return __builtin_amdgcn_fmed3f(a, b, c);
}

// ---------------- kNN ----------------
__global__ void knn_prep(const float* __restrict__ rgb, const float* __restrict__ ir,
                         float* __restrict__ xpack) {
    int t = blockIdx.x * blockDim.x + threadIdx.x;
    if (t >= 2 * NB * HWT) return;
    int nm = t / HWT, j = t - nm * HWT;
    int mod = nm / NB, n = nm - mod * NB;
    const float* x = (mod == 0 ? rgb : ir) + (size_t)n * 5 * HWT;
    float v[5], q = 0.f;
#pragma unroll
    for (int d = 0; d < 5; ++d) { v[d] = x[d * HWT + j]; q = fmaf(v[d], v[d], q); }
    float* o = xpack + (size_t)t * 8;
#pragma unroll
    for (int d = 0; d < 5; ++d) o[d] = v[d];
    o[5] = q; o[6] = 0.f; o[7] = 0.f;
}

__global__ __launch_bounds__(256) void knn_main(const float* __restrict__ xpack,
                                                unsigned* __restrict__ partial) {
    int seg = blockIdx.x, rb = blockIdx.y, nm = blockIdx.z;
    int t = threadIdx.x;
    int row0 = rb * (256 * RPT) + t * RPT;
    const float* xp = xpack + (size_t)nm * HWT * 8;
    __shared__ float4 xs[TILE * 2];

    float xi[RPT][5], qi1[RPT];
#pragma unroll
    for (int r = 0; r < RPT; ++r) {
        int row = row0 + r;
        int rr = (row < HWT) ? row : (HWT - 1);
        float4 a = ((const float4*)xp)[rr * 2];
        float4 b = ((const float4*)xp)[rr * 2 + 1];
        xi[r][0] = a.x; xi[r][1] = a.y; xi[r][2] = a.z; xi[r][3] = a.w; xi[r][4] = b.x;
        qi1[r] = b.y + 1.0f;
    }
    const float BIG = __uint_as_float(0x7F000000u);
    float best[RPT][8];
#pragma unroll
    for (int r = 0; r < RPT; ++r)
#pragma unroll
        for (int i = 0; i < 8; ++i) best[r][i] = BIG;

    int jbase = seg * (TPS * TILE);
    for (int tl = 0; tl < TPS; ++tl) {
        int j0 = jbase + tl * TILE;
        __syncthreads();
        if (t < TILE * 2) xs[t] = ((const float4*)xp)[j0 * 2 + t];
        __syncthreads();
        for (int jj = 0; jj < TILE; ++jj) {
            float4 a = xs[jj * 2];
            float4 b = xs[jj * 2 + 1];
            unsigned jg = (unsigned)(j0 + jj);
#pragma unroll
            for (int r = 0; r < RPT; ++r) {
                float dot = a.x * xi[r][0];
                dot = fmaf(a.y, xi[r][1], dot);
                dot = fmaf(a.z, xi[r][2], dot);
                dot = fmaf(a.w, xi[r][3], dot);
                dot = fmaf(b.x, xi[r][4], dot);
                float d2 = fmaf(-2.0f, dot, b.y + qi1[r]);
                unsigned kb = (__float_as_uint(d2) & 0xFFFFF000u) | jg;
                float kf = __uint_as_float(kb);
                best[r][7] = med3f(best[r][6], best[r][7], kf);
                best[r][6] = med3f(best[r][5], best[r][6], kf);
                best[r][5] = med3f(best[r][4], best[r][5], kf);
                best[r][4] = med3f(best[r][3], best[r][4], kf);
                best[r][3] = med3f(best[r][2], best[r][3], kf);
                best[r][2] = med3f(best[r][1], best[r][2], kf);
                best[r][1] = med3f(best[r][0], best[r][1], kf);
                best[r][0] = fminf(best[r][0], kf);
            }
        }
    }
#pragma unroll
    for (int r = 0; r < RPT; ++r) {
        int row = row0 + r;
        if (row < HWT) {
            unsigned* o = partial + (((size_t)nm * S_SEG + seg) * HWT + row) * 8;
            uint4 lo = { __float_as_uint(best[r][0]), __float_as_uint(best[r][1]),
                         __float_as_uint(best[r][2]), __float_as_uint(best[r][3]) };
            uint4 hi = { __float_as_uint(best[r][4]), __float_as_uint(best[r][5]),
                         __float_as_uint(best[r][6]), __float_as_uint(best[r][7]) };
            ((uint4*)o)[0] = lo;
            ((uint4*)o)[1] = hi;
        }
    }
}

__global__ __launch_bounds__(256) void knn_merge(const unsigned* __restrict__ partial,
                                                 int* __restrict__ knn_rgb,
                                                 int* __restrict__ knn_ir) {
    int tid = blockIdx.x * blockDim.x + threadIdx.x;
    if (tid >= 2 * 2 * NB * HWT) return;
    int rid = tid >> 1, sub = tid & 1;
    int nm = rid / HWT, row = rid - nm * HWT;
    const float BIG = __uint_as_float(0x7F000000u);
    float best[8];
#pragma unroll
    for (int i = 0; i < 8; ++i) best[i] = BIG;
    for (int s = sub; s < S_SEG; s += 2) {
        const unsigned* p = partial + (((size_t)nm * S_SEG + s) * HWT + row) * 8;
#pragma unroll
        for (int w = 0; w < 2; ++w) {
            uint4 v = ((const uint4*)p)[w];
            unsigned vv[4] = { v.x, v.y, v.z, v.w };
#pragma unroll
            for (int e = 0; e < 4; ++e) {
                float kf = __uint_as_float(vv[e]);
                best[7] = med3f(best[6], best[7], kf);
                best[6] = med3f(best[5], best[6], kf);
                best[5] = med3f(best[4], best[5], kf);
                best[4] = med3f(best[3], best[4], kf);
                best[3] = med3f(best[2], best[3], kf);
                best[2] = med3f(best[1], best[2], kf);
                best[1] = med3f(best[0], best[1], kf);
                best[0] = fminf(best[0], kf);
            }
        }
    }
    float other[8];
#pragma unroll
    for (int i = 0; i < 8; ++i) other[i] = __shfl_xor(best[i], 1);
#pragma unroll
    for (int i = 0; i < 8; ++i) {
        float kf = other[i];
        best[7] = med3f(best[6], best[7], kf);
        best[6] = med3f(best[5], best[6], kf);
        best[5] = med3f(best[4], best[5], kf);
        best[4] = med3f(best[3], best[4], kf);
        best[3] = med3f(best[2], best[3], kf);
        best[2] = med3f(best[1], best[2], kf);
        best[1] = med3f(best[0], best[1], kf);
        best[0] = fminf(best[0], kf);
    }
    if (sub == 0) {
        int mod = nm / NB, n = nm - mod * NB;
        int* o = (mod == 0 ? knn_rgb : knn_ir) + ((size_t)n * HWT + row) * KNN;
#pragma unroll
        for (int i = 0; i < 8; ++i) o[i] = (int)(__float_as_uint(best[i]) & 0xFFFu);
    }
}

// ---------------- weight prep ----------------
__global__ void init_kernel(const float* __restrict__ Wg_rgb, const float* __restrict__ Wg_ir,
                            float* __restrict__ Wcomb, float* __restrict__ g) {
    int t = blockIdx.x * blockDim.x + threadIdx.x;
    if (t < 1024 * 256) {
        int o = t >> 8, j = t & 255;
        float v;
        if (o < 256)      v = Wg_rgb[o * 512 + j] + Wg_rgb[o * 512 + 256 + j];
        else if (o < 512) v = Wg_rgb[(o - 256) * 512 + 256 + j];
        else if (o < 768) v = Wg_ir[(o - 512) * 512 + j] + Wg_ir[(o - 512) * 512 + 256 + j];
        else              v = Wg_ir[(o - 768) * 512 + 256 + j];
        Wcomb[t] = v;
    }
    if (t < NB * CH) g[t] = 1.0f;
}

__global__ __launch_bounds__(256) void scale_w(const float* __restrict__ Wcomb,
                                               const float* __restrict__ g,
                                               __hip_bfloat16* __restrict__ Wbf) {
    int n = blockIdx.y;
    int gid = blockIdx.x * 256 + threadIdx.x;
    int o = gid >> 5;
    int kb = (gid & 31) * 8;
    const float* w = Wcomb + o * 256 + kb;
    const float* gp = g + n * CH + kb;
    union { uint4 u; __hip_bfloat16 h[8]; } pk;
#pragma unroll
    for (int i = 0; i < 8; ++i) pk.h[i] = __float2bfloat16(w[i] * gp[i]);
    *(uint4*)(Wbf + ((size_t)n * 1024 + o) * CH + kb) = pk.u;
}

__global__ __launch_bounds__(256) void convert_a(const float* __restrict__ cnn,
                                                 __hip_bfloat16* __restrict__ Abf) {
    __shared__ float st[64][65];
    int n = blockIdx.z, k0 = blockIdx.y * 64, m0 = blockIdx.x * 64;
    int t = threadIdx.x;
    const float* src = cnn + (size_t)n * CH * HWT;
#pragma unroll
    for (int r = 0; r < 4; ++r) {
        int kl = r * 16 + (t >> 4);
        int ms = (t & 15) * 4;
        float4 v = {0.f, 0.f, 0.f, 0.f};
        if (m0 + ms < HWT) v = *(const float4*)(src + (size_t)(k0 + kl) * HWT + m0 + ms);
        st[ms + 0][kl] = v.x; st[ms + 1][kl] = v.y;
        st[ms + 2][kl] = v.z; st[ms + 3][kl] = v.w;
    }
    __syncthreads();
    int m = t >> 2, kg = (t & 3) * 16;
    union { uint4 u[2]; __hip_bfloat16 h[16]; } pk;
#pragma unroll
    for (int i = 0; i < 16; ++i) pk.h[i] = __float2bfloat16(st[m][kg + i]);
    __hip_bfloat16* dst = Abf + ((size_t)n * MPAD + m0 + m) * CH + k0 + kg;
    ((uint4*)dst)[0] = pk.u[0];
    ((uint4*)dst)[1] = pk.u[1];
}

// ---------------- MFMA GEMM ----------------
// grid (232, NB); w = (lid%8)*29 + lid/8 -> XCD-contiguous m-tiles (A reuse in L2)
// epilogue: C-tile bf16 in LDS with XOR(ml&15) swizzle; global stores LINEAR
// (permute on the LDS-read side) so each store instruction covers full lines.
__global__ __launch_bounds__(256) void gemm_mfma(const __hip_bfloat16* __restrict__ Abf,
                                                 const __hip_bfloat16* __restrict__ Wbf,
                                                 __hip_bfloat16* __restrict__ Yall) {
    __shared__ char smem[32768];
    char* sA = smem;
    char* sB = smem + 16384;
    int lid = blockIdx.x;
    int n = blockIdx.y;
    int w = (lid & 7) * 29 + (lid >> 3);
    int m0 = (w >> 3) * 128;
    int o0 = (w & 7) * 128;
    int t = threadIdx.x;
    int lane = t & 63, wid = t >> 6;
    int wm = wid >> 1, wo = wid & 1;

    const __hip_bfloat16* Ab = Abf + (size_t)n * MPAD * CH;
    const __hip_bfloat16* Wb = Wbf + (size_t)n * 1024 * CH;

    f32x4 acc[4][4] = {};

    int srow = t >> 3;
    int sslot = t & 7;
    int swz = (sslot ^ (srow & 7)) << 4;
    int fr = lane & 15;
    int kg = lane >> 4;
    int p = lane & 7;

    uint4 av[4], bv[4];
    auto load_tile = [&](int ks) {
#pragma unroll
        for (int r = 0; r < 4; ++r) {
            int row = srow + 32 * r;
            av[r] = *(const uint4*)(Ab + ((size_t)(m0 + row)) * CH + ks * 64 + sslot * 8);
            bv[r] = *(const uint4*)(Wb + ((size_t)(o0 + row)) * CH + ks * 64 + sslot * 8);
        }
    };
    load_tile(0);

    for (int ks = 0; ks < 4; ++ks) {
        __syncthreads();
#pragma unroll
        for (int r = 0; r < 4; ++r) {
            int row = srow + 32 * r;
            *(uint4*)(sA + row * 128 + swz) = av[r];
            *(uint4*)(sB + row * 128 + swz) = bv[r];
        }
        __syncthreads();
        if (ks < 3) load_tile(ks + 1);
#pragma unroll
        for (int kk = 0; kk < 2; ++kk) {
            bf16x8 hf[4], wf[4];
            int slot = kk * 4 + kg;
            int inrow = (slot ^ p) << 4;
#pragma unroll
            for (int f = 0; f < 4; ++f) {
                hf[f] = *(const bf16x8*)(sA + (wm * 64 + f * 16 + fr) * 128 + inrow);
                wf[f] = *(const bf16x8*)(sB + (wo * 64 + f * 16 + fr) * 128 + inrow);
            }
#pragma unroll
            for (int fa = 0; fa < 4; ++fa)
#pragma unroll
                for (int fb = 0; fb < 4; ++fb)
                    acc[fa][fb] = __builtin_amdgcn_mfma_f32_16x16x32_bf16(
                        wf[fa], hf[fb], acc[fa][fb], 0, 0, 0);
        }
    }

    // epilogue: acc -> LDS (bf16, XOR(ml&15) swizzle) -> linear coalesced global
    __syncthreads();
#pragma unroll
    for (int fa = 0; fa < 4; ++fa)
#pragma unroll
        for (int fb = 0; fb < 4; ++fb) {
            int ml = wm * 64 + fb * 16 + fr;            // local m (D col = lane&15)
            int ob = (wo * 64 + fa * 16 + kg * 4) * 2;  // local o byte (D row)
            f32x4 v = acc[fa][fb];
            union { ushort4 u; __hip_bfloat16 h[4]; } pk;
            pk.h[0] = __float2bfloat16(v.x);
            pk.h[1] = __float2bfloat16(v.y);
            pk.h[2] = __float2bfloat16(v.z);
            pk.h[3] = __float2bfloat16(v.w);
            int swzb = (ob & ~15) ^ ((ml & 15) << 4);
            *(ushort4*)(smem + ml * 256 + swzb + (ob & 15)) = pk.u;
        }
    __syncthreads();
    __hip_bfloat16* Y = Yall + (size_t)n * HWT * 1024;
    int colb = (t & 15) * 16;
#pragma unroll
    for (int i = 0; i < 8; ++i) {
        int row = i * 16 + (t >> 4);
        int grow = m0 + row;
        if (grow < HWT) {
            uint4 v = *(const uint4*)(smem + row * 256 + (colb ^ ((row & 15) << 4)));
            *(uint4*)((char*)Y + (size_t)grow * 2048 + o0 * 2 + colb) = v;
        }
    }
}

// ---------------- gather / SE / final ----------------
__global__ void zero_cc(float* __restrict__ ccsum) {
    int t = blockIdx.x * blockDim.x + threadIdx.x;
    if (t < NB * 512) ccsum[t] = 0.f;
}

// 1D grid 900; bijective XCD-chunk swizzle -> each XCD owns ~half a batch
__global__ __launch_bounds__(256) void gather_kernel(const __hip_bfloat16* __restrict__ Yall,
                                                     const int* __restrict__ knn_rgb,
                                                     const int* __restrict__ knn_ir,
                                                     const float* __restrict__ b_rgb,
                                                     const float* __restrict__ b_ir,
                                                     float* __restrict__ ccsum) {
    int lid = blockIdx.x;                 // 0..899
    int xcd = lid & 7, sub = lid >> 3;    // 900 = 8*112 + 4 -> q=112, r=4
    int wg = (xcd < 4 ? xcd * 113 : 4 * 113 + (xcd - 4) * 112) + sub;
    int n = wg / 225;
    int hwbase = (wg - n * 225) * POSB;
    int t = threadIdx.x;
    int half = t >> 7;
    int cp = (t & 127) << 1;
    __shared__ int sidx[POSB][2][KNN];    // 256 ints: one per thread
    {
        int p = t >> 4, rem = t & 15;
        int hw = hwbase + p;
        int v;
        if (rem < 8) v = knn_rgb[((size_t)n * HWT + hw) * KNN + rem];
        else         v = knn_ir[((size_t)n * HWT + hw) * KNN + (rem - 8)];
        sidx[p][rem >> 3][rem & 7] = v;
    }
    __syncthreads();
    const float* bias = half ? b_ir : b_rgb;
    float b0 = bias[cp], b1 = bias[cp + 1];
    float acc0 = 0.f, acc1 = 0.f;
    const __hip_bfloat16* Y = Yall + (size_t)n * HWT * 1024;
    int offA = half * 512 + cp;
    int offB = half * 512 + 256 + cp;
    for (int p = 0; p < POSB; ++p) {
        float m0 = 0.f, m1 = 0.f;
#pragma unroll
        for (int k = 0; k < KNN; ++k) {
            int jA = sidx[p][half][k];
            int jB = sidx[p][half ^ 1][k];
            unsigned u1 = *(const unsigned*)(Y + (size_t)jA * 1024 + offA);
            unsigned u2 = *(const unsigned*)(Y + (size_t)jB * 1024 + offB);
            float a0 = __uint_as_float(u1 << 16);
            float a1 = __uint_as_float(u1 & 0xFFFF0000u);
            float c0 = __uint_as_float(u2 << 16);
            float c1 = __uint_as_float(u2 & 0xFFFF0000u);
            m0 = fmaxf(m0, a0 - c0 + b0);
            m1 = fmaxf(m1, a1 - c1 + b1);
        }
        acc0 += m0;
        acc1 += m1;
    }
    atomicAdd(&ccsum[n * 512 + half * 256 + cp], acc0);
    atomicAdd(&ccsum[n * 512 + half * 256 + cp + 1], acc1);
}

__global__ __launch_bounds__(256) void se_kernel(const float* __restrict__ ccsum,
                                                 const float* __restrict__ W1,
                                                 const float* __restrict__ b1,
                                                 const float* __restrict__ W2,
                                                 const float* __restrict__ b2,
                                                 float* __restrict__ g) {
    int n = blockIdx.x;
    int t = threadIdx.x;
    __shared__ float hid[16];
    __shared__ float cc[512];
    cc[t] = ccsum[n * 512 + t] * (1.0f / HWT);
    cc[256 + t] = ccsum[n * 512 + 256 + t] * (1.0f / HWT);
    __syncthreads();
    if (t < 16) {
        float s = b1[t];
        for (int j = 0; j < 512; ++j) s = fmaf(W1[t * 512 + j], cc[j], s);
        hid[t] = fmaxf(s, 0.f);
    }
    __syncthreads();
    float s = b2[t];
#pragma unroll
    for (int q = 0; q < 16; ++q) s = fmaf(W2[t * 16 + q], hid[q], s);
    float se = 1.0f / (1.0f + expf(-s));
    g[n * CH + t] *= se;
}

__global__ void final_kernel(const float* __restrict__ cnn, const float* __restrict__ g,
                             const float* __restrict__ gamma, float* __restrict__ out) {
    int t = blockIdx.x * blockDim.x + threadIdx.x;
    if (t >= NB * CH * HWT / 4) return;
    int nc = (t * 4) / HWT;   // HWT % 4 == 0 -> uniform within the float4
    float4 x = ((const float4*)cnn)[t];
    float s = gamma[0] * g[nc] + 1.0f;
    float4 o;
    o.x = fmaxf(s * x.x, 0.f);
    o.y = fmaxf(s * x.y, 0.f);
    o.z = fmaxf(s * x.z, 0.f);
    o.w = fmaxf(s * x.w, 0.f);
    ((float4*)out)[t] = o;
}

extern "C" void kernel_launch(void* const* d_in, const int* in_sizes, int n_in,
                              void* d_out, int out_size, void* d_ws, size_t ws_size,
                              hipStream_t stream) {
    const float* cnn    = (const float*)d_in[0];
    const float* rgb    = (const float*)d_in[1];
    const float* ir     = (const float*)d_in[2];
    const float* Wg_rgb = (const float*)d_in[3];
    const float* bg_rgb = (const float*)d_in[4];
    const float* Wg_ir  = (const float*)d_in[5];
    const float* bg_ir  = (const float*)d_in[6];
    const float* Wse1   = (const float*)d_in[7];
    const float* bse1   = (const float*)d_in[8];
    const float* Wse2   = (const float*)d_in[9];
    const float* bse2   = (const float*)d_in[10];
    const float* gamma  = (const float*)d_in[11];
    float* out = (float*)d_out;

    char* ws = (char*)d_ws;
    size_t off = 0;
    float* xpack = (float*)(ws + off); off += (size_t)2 * NB * HWT * 8 * 4;
    int* knn_rgb = (int*)(ws + off); off += (size_t)NB * HWT * KNN * 4;
    int* knn_ir  = (int*)(ws + off); off += (size_t)NB * HWT * KNN * 4;
    float* Wcomb = (float*)(ws + off); off += (size_t)1024 * 256 * 4;
    __hip_bfloat16* Wbf = (__hip_bfloat16*)(ws + off); off += (size_t)NB * 1024 * CH * 2;
    __hip_bfloat16* Abf = (__hip_bfloat16*)(ws + off); off += (size_t)NB * MPAD * CH * 2;
    __hip_bfloat16* Yall = (__hip_bfloat16*)(ws + off);
    unsigned* partial = (unsigned*)Yall;  // aliases Y (27.6 MB < 29.5 MB), dead before gemm
    off += (size_t)NB * HWT * 1024 * 2;
    float* ccsum = (float*)(ws + off); off += (size_t)NB * 512 * 4;
    float* g     = (float*)(ws + off); off += (size_t)NB * CH * 4;

    knn_prep<<<(2 * NB * HWT + 255) / 256, 256, 0, stream>>>(rgb, ir, xpack);
    knn_main<<<dim3(S_SEG, RB, 2 * NB), 256, 0, stream>>>(xpack, partial);
    knn_merge<<<(4 * NB * HWT + 255) / 256, 256, 0, stream>>>(partial, knn_rgb, knn_ir);
    init_kernel<<<1024, 256, 0, stream>>>(Wg_rgb, Wg_ir, Wcomb, g);
    convert_a<<<dim3(MPAD / 64, 4, NB), 256, 0, stream>>>(cnn, Abf);

    for (int it = 0; it < ITERS; ++it) {
        scale_w<<<dim3(128, NB), 256, 0, stream>>>(Wcomb, g, Wbf);
        gemm_mfma<<<dim3(232, NB), 256, 0, stream>>>(Abf, Wbf, Yall);
        zero_cc<<<8, 256, 0, stream>>>(ccsum);
        gather_kernel<<<NB * HWT / POSB, 256, 0, stream>>>(Yall, knn_rgb, knn_ir,
                                                           bg_rgb, bg_ir, ccsum);
        se_kernel<<<NB, 256, 0, stream>>>(ccsum, Wse1, bse1, Wse2, bse2, g);
    }
    final_kernel<<<(NB * CH * HWT / 4 + 255) / 256, 256, 0, stream>>>(cnn, g, gamma, out);
}

// Round 7
// 240.667 us; speedup vs baseline: 1.4672x; 1.0299x over previous
//
#include <hip/hip_runtime.h>
#include <hip/hip_bf16.h>

#define NB 4
#define CH 256
#define HWT 3600
#define KNN 8
#define ITERS 2
#define POSB 16
#define MPAD 3712

#define SSEG 16    // j-segments per row (16*225 = 3600)
#define SEGJ 225   // j per segment == rows per block

typedef __attribute__((ext_vector_type(8))) __bf16 bf16x8;
typedef __attribute__((ext_vector_type(4))) float f32x4;

__device__ inline float med3f(float a, float b, float c) {
    return __builtin_amdgcn_fmed3f(a, b, c);
}

// ---------------- kNN ----------------
__global__ void knn_prep(const float* __restrict__ rgb, const float* __restrict__ ir,
                         float* __restrict__ xpack) {
    int t = blockIdx.x * blockDim.x + threadIdx.x;
    if (t >= 2 * NB * HWT) return;
    int nm = t / HWT, j = t - nm * HWT;
    int mod = nm / NB, n = nm - mod * NB;
    const float* x = (mod == 0 ? rgb : ir) + (size_t)n * 5 * HWT;
    float v[5], q = 0.f;
#pragma unroll
    for (int d = 0; d < 5; ++d) { v[d] = x[d * HWT + j]; q = fmaf(v[d], v[d], q); }
    float* o = xpack + (size_t)t * 8;
#pragma unroll
    for (int d = 0; d < 5; ++d) o[d] = v[d];
    o[5] = q; o[6] = 0.f; o[7] = 0.f;
}

// grid (SSEG, 16, 2*NB) = 2048 blocks (exactly 8/CU). One LDS stage + one barrier
// per block; 225 rows x 225 candidates; branchless med3 top-8 insert.
__global__ __launch_bounds__(256) void knn_main(const float* __restrict__ xpack,
                                                unsigned* __restrict__ partial) {
    int seg = blockIdx.x, rb = blockIdx.y, nm = blockIdx.z;
    int t = threadIdx.x;
    const float* xp = xpack + (size_t)nm * HWT * 8;
    __shared__ float4 xs[SEGJ * 2];
    const float4* src = ((const float4*)xp) + seg * (SEGJ * 2);
    xs[t] = src[t];                         // t < 450 always (256 <= 450)
    if (t + 256 < SEGJ * 2) xs[t + 256] = src[t + 256];
    __syncthreads();

    int row = rb * SEGJ + t;                // 16*225 == 3600, no row padding
    bool active = (t < SEGJ);
    int rr = active ? row : 0;
    float4 a0 = ((const float4*)xp)[rr * 2];
    float4 b0 = ((const float4*)xp)[rr * 2 + 1];
    float xi0 = a0.x, xi1 = a0.y, xi2 = a0.z, xi3 = a0.w, xi4 = b0.x;
    float qi1 = b0.y + 1.0f;

    const float BIG = __uint_as_float(0x7F000000u);
    float best[8];
#pragma unroll
    for (int i = 0; i < 8; ++i) best[i] = BIG;

    const float2* xs2 = (const float2*)xs;
    unsigned jg0 = (unsigned)(seg * SEGJ);
#pragma unroll 5
    for (int jj = 0; jj < SEGJ; ++jj) {
        float4 a = xs[jj * 2];
        float2 b = xs2[jj * 4 + 2];         // {x4, q_j}
        float dot = a.x * xi0;
        dot = fmaf(a.y, xi1, dot);
        dot = fmaf(a.z, xi2, dot);
        dot = fmaf(a.w, xi3, dot);
        dot = fmaf(b.x, xi4, dot);
        float d2 = fmaf(-2.0f, dot, b.y + qi1);      // d^2 + 1 >= ~1
        unsigned kb = (__float_as_uint(d2) & 0xFFFFF000u) | (jg0 + jj);
        float kf = __uint_as_float(kb);
        best[7] = med3f(best[6], best[7], kf);
        best[6] = med3f(best[5], best[6], kf);
        best[5] = med3f(best[4], best[5], kf);
        best[4] = med3f(best[3], best[4], kf);
        best[3] = med3f(best[2], best[3], kf);
        best[2] = med3f(best[1], best[2], kf);
        best[1] = med3f(best[0], best[1], kf);
        best[0] = fminf(best[0], kf);
    }
    if (active) {
        unsigned* o = partial + (((size_t)nm * SSEG + seg) * HWT + row) * 8;
        uint4 lo = { __float_as_uint(best[0]), __float_as_uint(best[1]),
                     __float_as_uint(best[2]), __float_as_uint(best[3]) };
        uint4 hi = { __float_as_uint(best[4]), __float_as_uint(best[5]),
                     __float_as_uint(best[6]), __float_as_uint(best[7]) };
        ((uint4*)o)[0] = lo;
        ((uint4*)o)[1] = hi;
    }
}

// 2 lanes per row: each merges 8 segments, then shuffle-exchange final merge
__global__ __launch_bounds__(256) void knn_merge(const unsigned* __restrict__ partial,
                                                 int* __restrict__ knn_rgb,
                                                 int* __restrict__ knn_ir) {
    int tid = blockIdx.x * blockDim.x + threadIdx.x;
    if (tid >= 2 * 2 * NB * HWT) return;
    int rid = tid >> 1, sub = tid & 1;
    int nm = rid / HWT, row = rid - nm * HWT;
    const float BIG = __uint_as_float(0x7F000000u);
    float best[8];
#pragma unroll
    for (int i = 0; i < 8; ++i) best[i] = BIG;
    for (int s = sub; s < SSEG; s += 2) {
        const unsigned* p = partial + (((size_t)nm * SSEG + s) * HWT + row) * 8;
#pragma unroll
        for (int w = 0; w < 2; ++w) {
            uint4 v = ((const uint4*)p)[w];
            unsigned vv[4] = { v.x, v.y, v.z, v.w };
#pragma unroll
            for (int e = 0; e < 4; ++e) {
                float kf = __uint_as_float(vv[e]);
                best[7] = med3f(best[6], best[7], kf);
                best[6] = med3f(best[5], best[6], kf);
                best[5] = med3f(best[4], best[5], kf);
                best[4] = med3f(best[3], best[4], kf);
                best[3] = med3f(best[2], best[3], kf);
                best[2] = med3f(best[1], best[2], kf);
                best[1] = med3f(best[0], best[1], kf);
                best[0] = fminf(best[0], kf);
            }
        }
    }
    float other[8];
#pragma unroll
    for (int i = 0; i < 8; ++i) other[i] = __shfl_xor(best[i], 1);
#pragma unroll
    for (int i = 0; i < 8; ++i) {
        float kf = other[i];
        best[7] = med3f(best[6], best[7], kf);
        best[6] = med3f(best[5], best[6], kf);
        best[5] = med3f(best[4], best[5], kf);
        best[4] = med3f(best[3], best[4], kf);
        best[3] = med3f(best[2], best[3], kf);
        best[2] = med3f(best[1], best[2], kf);
        best[1] = med3f(best[0], best[1], kf);
        best[0] = fminf(best[0], kf);
    }
    if (sub == 0) {
        int mod = nm / NB, n = nm - mod * NB;
        int* o = (mod == 0 ? knn_rgb : knn_ir) + ((size_t)n * HWT + row) * KNN;
#pragma unroll
        for (int i = 0; i < 8; ++i) o[i] = (int)(__float_as_uint(best[i]) & 0xFFFu);
    }
}

// ---------------- weight prep ----------------
__global__ void init_kernel(const float* __restrict__ Wg_rgb, const float* __restrict__ Wg_ir,
                            float* __restrict__ Wcomb, float* __restrict__ g) {
    int t = blockIdx.x * blockDim.x + threadIdx.x;
    if (t < 1024 * 256) {
        int o = t >> 8, j = t & 255;
        float v;
        if (o < 256)      v = Wg_rgb[o * 512 + j] + Wg_rgb[o * 512 + 256 + j];
        else if (o < 512) v = Wg_rgb[(o - 256) * 512 + 256 + j];
        else if (o < 768) v = Wg_ir[(o - 512) * 512 + j] + Wg_ir[(o - 512) * 512 + 256 + j];
        else              v = Wg_ir[(o - 768) * 512 + 256 + j];
        Wcomb[t] = v;
    }
    if (t < NB * CH) g[t] = 1.0f;
}

__global__ __launch_bounds__(256) void scale_w(const float* __restrict__ Wcomb,
                                               const float* __restrict__ g,
                                               __hip_bfloat16* __restrict__ Wbf) {
    int n = blockIdx.y;
    int gid = blockIdx.x * 256 + threadIdx.x;
    int o = gid >> 5;
    int kb = (gid & 31) * 8;
    const float* w = Wcomb + o * 256 + kb;
    const float* gp = g + n * CH + kb;
    union { uint4 u; __hip_bfloat16 h[8]; } pk;
#pragma unroll
    for (int i = 0; i < 8; ++i) pk.h[i] = __float2bfloat16(w[i] * gp[i]);
    *(uint4*)(Wbf + ((size_t)n * 1024 + o) * CH + kb) = pk.u;
}

__global__ __launch_bounds__(256) void convert_a(const float* __restrict__ cnn,
                                                 __hip_bfloat16* __restrict__ Abf) {
    __shared__ float st[64][65];
    int n = blockIdx.z, k0 = blockIdx.y * 64, m0 = blockIdx.x * 64;
    int t = threadIdx.x;
    const float* src = cnn + (size_t)n * CH * HWT;
#pragma unroll
    for (int r = 0; r < 4; ++r) {
        int kl = r * 16 + (t >> 4);
        int ms = (t & 15) * 4;
        float4 v = {0.f, 0.f, 0.f, 0.f};
        if (m0 + ms < HWT) v = *(const float4*)(src + (size_t)(k0 + kl) * HWT + m0 + ms);
        st[ms + 0][kl] = v.x; st[ms + 1][kl] = v.y;
        st[ms + 2][kl] = v.z; st[ms + 3][kl] = v.w;
    }
    __syncthreads();
    int m = t >> 2, kg = (t & 3) * 16;
    union { uint4 u[2]; __hip_bfloat16 h[16]; } pk;
#pragma unroll
    for (int i = 0; i < 16; ++i) pk.h[i] = __float2bfloat16(st[m][kg + i]);
    __hip_bfloat16* dst = Abf + ((size_t)n * MPAD + m0 + m) * CH + k0 + kg;
    ((uint4*)dst)[0] = pk.u[0];
    ((uint4*)dst)[1] = pk.u[1];
}

// ---------------- MFMA GEMM ----------------
__global__ __launch_bounds__(256) void gemm_mfma(const __hip_bfloat16* __restrict__ Abf,
                                                 const __hip_bfloat16* __restrict__ Wbf,
                                                 __hip_bfloat16* __restrict__ Yall) {
    __shared__ char smem[32768];
    char* sA = smem;
    char* sB = smem + 16384;
    int lid = blockIdx.x;
    int n = blockIdx.y;
    int w = (lid & 7) * 29 + (lid >> 3);
    int m0 = (w >> 3) * 128;
    int o0 = (w & 7) * 128;
    int t = threadIdx.x;
    int lane = t & 63, wid = t >> 6;
    int wm = wid >> 1, wo = wid & 1;

    const __hip_bfloat16* Ab = Abf + (size_t)n * MPAD * CH;
    const __hip_bfloat16* Wb = Wbf + (size_t)n * 1024 * CH;

    f32x4 acc[4][4] = {};

    int srow = t >> 3;
    int sslot = t & 7;
    int swz = (sslot ^ (srow & 7)) << 4;
    int fr = lane & 15;
    int kg = lane >> 4;
    int p = lane & 7;

    uint4 av[4], bv[4];
    auto load_tile = [&](int ks) {
#pragma unroll
        for (int r = 0; r < 4; ++r) {
            int row = srow + 32 * r;
            av[r] = *(const uint4*)(Ab + ((size_t)(m0 + row)) * CH + ks * 64 + sslot * 8);
            bv[r] = *(const uint4*)(Wb + ((size_t)(o0 + row)) * CH + ks * 64 + sslot * 8);
        }
    };
    load_tile(0);

    for (int ks = 0; ks < 4; ++ks) {
        __syncthreads();
#pragma unroll
        for (int r = 0; r < 4; ++r) {
            int row = srow + 32 * r;
            *(uint4*)(sA + row * 128 + swz) = av[r];
            *(uint4*)(sB + row * 128 + swz) = bv[r];
        }
        __syncthreads();
        if (ks < 3) load_tile(ks + 1);
#pragma unroll
        for (int kk = 0; kk < 2; ++kk) {
            bf16x8 hf[4], wf[4];
            int slot = kk * 4 + kg;
            int inrow = (slot ^ p) << 4;
#pragma unroll
            for (int f = 0; f < 4; ++f) {
                hf[f] = *(const bf16x8*)(sA + (wm * 64 + f * 16 + fr) * 128 + inrow);
                wf[f] = *(const bf16x8*)(sB + (wo * 64 + f * 16 + fr) * 128 + inrow);
            }
#pragma unroll
            for (int fa = 0; fa < 4; ++fa)
#pragma unroll
                for (int fb = 0; fb < 4; ++fb)
                    acc[fa][fb] = __builtin_amdgcn_mfma_f32_16x16x32_bf16(
                        wf[fa], hf[fb], acc[fa][fb], 0, 0, 0);
        }
    }

    // epilogue: acc -> LDS (bf16, XOR(ml&15) swizzle) -> linear coalesced global
    __syncthreads();
#pragma unroll
    for (int fa = 0; fa < 4; ++fa)
#pragma unroll
        for (int fb = 0; fb < 4; ++fb) {
            int ml = wm * 64 + fb * 16 + fr;
            int ob = (wo * 64 + fa * 16 + kg * 4) * 2;
            f32x4 v = acc[fa][fb];
            union { ushort4 u; __hip_bfloat16 h[4]; } pk;
            pk.h[0] = __float2bfloat16(v.x);
            pk.h[1] = __float2bfloat16(v.y);
            pk.h[2] = __float2bfloat16(v.z);
            pk.h[3] = __float2bfloat16(v.w);
            int swzb = (ob & ~15) ^ ((ml & 15) << 4);
            *(ushort4*)(smem + ml * 256 + swzb + (ob & 15)) = pk.u;
        }
    __syncthreads();
    __hip_bfloat16* Y = Yall + (size_t)n * HWT * 1024;
    int colb = (t & 15) * 16;
#pragma unroll
    for (int i = 0; i < 8; ++i) {
        int row = i * 16 + (t >> 4);
        int grow = m0 + row;
        if (grow < HWT) {
            uint4 v = *(const uint4*)(smem + row * 256 + (colb ^ ((row & 15) << 4)));
            *(uint4*)((char*)Y + (size_t)grow * 2048 + o0 * 2 + colb) = v;
        }
    }
}

// ---------------- gather / SE / final ----------------
__global__ void zero_cc(float* __restrict__ ccsum) {
    int t = blockIdx.x * blockDim.x + threadIdx.x;
    if (t < NB * 512) ccsum[t] = 0.f;
}

__global__ __launch_bounds__(256) void gather_kernel(const __hip_bfloat16* __restrict__ Yall,
                                                     const int* __restrict__ knn_rgb,
                                                     const int* __restrict__ knn_ir,
                                                     const float* __restrict__ b_rgb,
                                                     const float* __restrict__ b_ir,
                                                     float* __restrict__ ccsum) {
    int lid = blockIdx.x;                 // 0..899
    int xcd = lid & 7, sub = lid >> 3;    // 900 = 8*112 + 4 -> q=112, r=4
    int wg = (xcd < 4 ? xcd * 113 : 4 * 113 + (xcd - 4) * 112) + sub;
    int n = wg / 225;
    int hwbase = (wg - n * 225) * POSB;
    int t = threadIdx.x;
    int half = t >> 7;
    int cp = (t & 127) << 1;
    __shared__ int sidx[POSB][2][KNN];
    {
        int p = t >> 4, rem = t & 15;
        int hw = hwbase + p;
        int v;
        if (rem < 8) v = knn_rgb[((size_t)n * HWT + hw) * KNN + rem];
        else         v = knn_ir[((size_t)n * HWT + hw) * KNN + (rem - 8)];
        sidx[p][rem >> 3][rem & 7] = v;
    }
    __syncthreads();
    const float* bias = half ? b_ir : b_rgb;
    float b0 = bias[cp], b1 = bias[cp + 1];
    float acc0 = 0.f, acc1 = 0.f;
    const __hip_bfloat16* Y = Yall + (size_t)n * HWT * 1024;
    int offA = half * 512 + cp;
    int offB = half * 512 + 256 + cp;
    for (int p = 0; p < POSB; ++p) {
        float m0 = 0.f, m1 = 0.f;
#pragma unroll
        for (int k = 0; k < KNN; ++k) {
            int jA = sidx[p][half][k];
            int jB = sidx[p][half ^ 1][k];
            unsigned u1 = *(const unsigned*)(Y + (size_t)jA * 1024 + offA);
            unsigned u2 = *(const unsigned*)(Y + (size_t)jB * 1024 + offB);
            float a0 = __uint_as_float(u1 << 16);
            float a1 = __uint_as_float(u1 & 0xFFFF0000u);
            float c0 = __uint_as_float(u2 << 16);
            float c1 = __uint_as_float(u2 & 0xFFFF0000u);
            m0 = fmaxf(m0, a0 - c0 + b0);
            m1 = fmaxf(m1, a1 - c1 + b1);
        }
        acc0 += m0;
        acc1 += m1;
    }
    atomicAdd(&ccsum[n * 512 + half * 256 + cp], acc0);
    atomicAdd(&ccsum[n * 512 + half * 256 + cp + 1], acc1);
}

__global__ __launch_bounds__(256) void se_kernel(const float* __restrict__ ccsum,
                                                 const float* __restrict__ W1,
                                                 const float* __restrict__ b1,
                                                 const float* __restrict__ W2,
                                                 const float* __restrict__ b2,
                                                 float* __restrict__ g) {
    int n = blockIdx.x;
    int t = threadIdx.x;
    __shared__ float hid[16];
    __shared__ float cc[512];
    cc[t] = ccsum[n * 512 + t] * (1.0f / HWT);
    cc[256 + t] = ccsum[n * 512 + 256 + t] * (1.0f / HWT);
    __syncthreads();
    if (t < 16) {
        float s = b1[t];
        for (int j = 0; j < 512; ++j) s = fmaf(W1[t * 512 + j], cc[j], s);
        hid[t] = fmaxf(s, 0.f);
    }
    __syncthreads();
    float s = b2[t];
#pragma unroll
    for (int q = 0; q < 16; ++q) s = fmaf(W2[t * 16 + q], hid[q], s);
    float se = 1.0f / (1.0f + expf(-s));
    g[n * CH + t] *= se;
}

__global__ void final_kernel(const float* __restrict__ cnn, const float* __restrict__ g,
                             const float* __restrict__ gamma, float* __restrict__ out) {
    int t = blockIdx.x * blockDim.x + threadIdx.x;
    if (t >= NB * CH * HWT / 4) return;
    int nc = (t * 4) / HWT;
    float4 x = ((const float4*)cnn)[t];
    float s = gamma[0] * g[nc] + 1.0f;
    float4 o;
    o.x = fmaxf(s * x.x, 0.f);
    o.y = fmaxf(s * x.y, 0.f);
    o.z = fmaxf(s * x.z, 0.f);
    o.w = fmaxf(s * x.w, 0.f);
    ((float4*)out)[t] = o;
}

extern "C" void kernel_launch(void* const* d_in, const int* in_sizes, int n_in,
                              void* d_out, int out_size, void* d_ws, size_t ws_size,
                              hipStream_t stream) {
    const float* cnn    = (const float*)d_in[0];
    const float* rgb    = (const float*)d_in[1];
    const float* ir     = (const float*)d_in[2];
    const float* Wg_rgb = (const float*)d_in[3];
    const float* bg_rgb = (const float*)d_in[4];
    const float* Wg_ir  = (const float*)d_in[5];
    const float* bg_ir  = (const float*)d_in[6];
    const float* Wse1   = (const float*)d_in[7];
    const float* bse1   = (const float*)d_in[8];
    const float* Wse2   = (const float*)d_in[9];
    const float* bse2   = (const float*)d_in[10];
    const float* gamma  = (const float*)d_in[11];
    float* out = (float*)d_out;

    char* ws = (char*)d_ws;
    size_t off = 0;
    float* xpack = (float*)(ws + off); off += (size_t)2 * NB * HWT * 8 * 4;
    int* knn_rgb = (int*)(ws + off); off += (size_t)NB * HWT * KNN * 4;
    int* knn_ir  = (int*)(ws + off); off += (size_t)NB * HWT * KNN * 4;
    float* Wcomb = (float*)(ws + off); off += (size_t)1024 * 256 * 4;
    __hip_bfloat16* Wbf = (__hip_bfloat16*)(ws + off); off += (size_t)NB * 1024 * CH * 2;
    __hip_bfloat16* Abf = (__hip_bfloat16*)(ws + off); off += (size_t)NB * MPAD * CH * 2;
    __hip_bfloat16* Yall = (__hip_bfloat16*)(ws + off);
    unsigned* partial = (unsigned*)Yall;  // aliases Y (14.7 MB < 29.5 MB), dead before gemm
    off += (size_t)NB * HWT * 1024 * 2;
    float* ccsum = (float*)(ws + off); off += (size_t)NB * 512 * 4;
    float* g     = (float*)(ws + off); off += (size_t)NB * CH * 4;

    knn_prep<<<(2 * NB * HWT + 255) / 256, 256, 0, stream>>>(rgb, ir, xpack);
    knn_main<<<dim3(SSEG, 16, 2 * NB), 256, 0, stream>>>(xpack, partial);
    knn_merge<<<(4 * NB * HWT + 255) / 256, 256, 0, stream>>>(partial, knn_rgb, knn_ir);
    init_kernel<<<1024, 256, 0, stream>>>(Wg_rgb, Wg_ir, Wcomb, g);
    convert_a<<<dim3(MPAD / 64, 4, NB), 256, 0, stream>>>(cnn, Abf);

    for (int it = 0; it < ITERS; ++it) {
        scale_w<<<dim3(128, NB), 256, 0, stream>>>(Wcomb, g, Wbf);
        gemm_mfma<<<dim3(232, NB), 256, 0, stream>>>(Abf, Wbf, Yall);
        zero_cc<<<8, 256, 0, stream>>>(ccsum);
        gather_kernel<<<NB * HWT / POSB, 256, 0, stream>>>(Yall, knn_rgb, knn_ir,
                                                           bg_rgb, bg_ir, ccsum);
        se_kernel<<<NB, 256, 0, stream>>>(ccsum, Wse1, bse1, Wse2, bse2, g);
    }
    final_kernel<<<(NB * CH * HWT / 4 + 255) / 256, 256, 0, stream>>>(cnn, g, gamma, out);
}

// Round 8
// 231.064 us; speedup vs baseline: 1.5282x; 1.0416x over previous
//
#include <hip/hip_runtime.h>
#include <hip/hip_bf16.h>

#define NB 4
#define CH 256
#define HWT 3600
#define KNN 8
#define POSB 16
#define MPAD 3712

#define SSEGP 8      // partial segments per row (450 candidates each)
#define SEGC 450     // candidates per knn segment
#define ROWB 225     // rows per knn block (16 row-blocks)

#define GEMM_BLKS 928     // 232 * NB
#define KNN_BLKS 1024     // 8 seg * 16 rb * 8 nm
#define B_BLKS 1952

typedef __attribute__((ext_vector_type(8))) __bf16 bf16x8;
typedef __attribute__((ext_vector_type(4))) float f32x4;

__device__ inline float med3f(float a, float b, float c) {
    return __builtin_amdgcn_fmed3f(a, b, c);
}

// ================= device bodies =================

__device__ __forceinline__ void gemm_body(int lid, int n,
                                          const __hip_bfloat16* __restrict__ Abf,
                                          const __hip_bfloat16* __restrict__ Wbf,
                                          __hip_bfloat16* __restrict__ Yall,
                                          char* smem) {
    char* sA = smem;
    char* sB = smem + 16384;
    int w = (lid & 7) * 29 + (lid >> 3);
    int m0 = (w >> 3) * 128;
    int o0 = (w & 7) * 128;
    int t = threadIdx.x;
    int lane = t & 63, wid = t >> 6;
    int wm = wid >> 1, wo = wid & 1;

    const __hip_bfloat16* Ab = Abf + (size_t)n * MPAD * CH;
    const __hip_bfloat16* Wb = Wbf + (size_t)n * 1024 * CH;

    f32x4 acc[4][4] = {};

    int srow = t >> 3;
    int sslot = t & 7;
    int swz = (sslot ^ (srow & 7)) << 4;
    int fr = lane & 15;
    int kg = lane >> 4;
    int p = lane & 7;

    uint4 av[4], bv[4];
    auto load_tile = [&](int ks) {
#pragma unroll
        for (int r = 0; r < 4; ++r) {
            int row = srow + 32 * r;
            av[r] = *(const uint4*)(Ab + ((size_t)(m0 + row)) * CH + ks * 64 + sslot * 8);
            bv[r] = *(const uint4*)(Wb + ((size_t)(o0 + row)) * CH + ks * 64 + sslot * 8);
        }
    };
    load_tile(0);

    for (int ks = 0; ks < 4; ++ks) {
        __syncthreads();
#pragma unroll
        for (int r = 0; r < 4; ++r) {
            int row = srow + 32 * r;
            *(uint4*)(sA + row * 128 + swz) = av[r];
            *(uint4*)(sB + row * 128 + swz) = bv[r];
        }
        __syncthreads();
        if (ks < 3) load_tile(ks + 1);
#pragma unroll
        for (int kk = 0; kk < 2; ++kk) {
            bf16x8 hf[4], wf[4];
            int slot = kk * 4 + kg;
            int inrow = (slot ^ p) << 4;
#pragma unroll
            for (int f = 0; f < 4; ++f) {
                hf[f] = *(const bf16x8*)(sA + (wm * 64 + f * 16 + fr) * 128 + inrow);
                wf[f] = *(const bf16x8*)(sB + (wo * 64 + f * 16 + fr) * 128 + inrow);
            }
#pragma unroll
            for (int fa = 0; fa < 4; ++fa)
#pragma unroll
                for (int fb = 0; fb < 4; ++fb)
                    acc[fa][fb] = __builtin_amdgcn_mfma_f32_16x16x32_bf16(
                        wf[fa], hf[fb], acc[fa][fb], 0, 0, 0);
        }
    }

    __syncthreads();
#pragma unroll
    for (int fa = 0; fa < 4; ++fa)
#pragma unroll
        for (int fb = 0; fb < 4; ++fb) {
            int ml = wm * 64 + fb * 16 + fr;
            int ob = (wo * 64 + fa * 16 + kg * 4) * 2;
            f32x4 v = acc[fa][fb];
            union { ushort4 u; __hip_bfloat16 h[4]; } pk;
            pk.h[0] = __float2bfloat16(v.x);
            pk.h[1] = __float2bfloat16(v.y);
            pk.h[2] = __float2bfloat16(v.z);
            pk.h[3] = __float2bfloat16(v.w);
            int swzb = (ob & ~15) ^ ((ml & 15) << 4);
            *(ushort4*)(smem + ml * 256 + swzb + (ob & 15)) = pk.u;
        }
    __syncthreads();
    __hip_bfloat16* Y = Yall + (size_t)n * HWT * 1024;
    int colb = (t & 15) * 16;
#pragma unroll
    for (int i = 0; i < 8; ++i) {
        int row = i * 16 + (t >> 4);
        int grow = m0 + row;
        if (grow < HWT) {
            uint4 v = *(const uint4*)(smem + row * 256 + (colb ^ ((row & 15) << 4)));
            *(uint4*)((char*)Y + (size_t)grow * 2048 + o0 * 2 + colb) = v;
        }
    }
}

__device__ __forceinline__ void knn_body(int kid, const float* __restrict__ xpack,
                                         unsigned* __restrict__ partial, char* smem) {
    int seg = kid & 7;
    int rb = (kid >> 3) & 15;
    int nm = kid >> 7;
    int t = threadIdx.x;
    const float* xp = xpack + (size_t)nm * HWT * 8;
    float4* xs4 = (float4*)smem;
    float2* xs2 = (float2*)(smem + SEGC * 16);
    int j0 = seg * SEGC;
    for (int i = t; i < SEGC; i += 256) {
        const float4* s = (const float4*)(xp + (size_t)(j0 + i) * 8);
        float4 a = s[0];
        float4 b = s[1];
        xs4[i] = a;
        float2 tmp; tmp.x = b.x; tmp.y = b.y;
        xs2[i] = tmp;
    }
    __syncthreads();

    int row = rb * ROWB + t;
    bool active = (t < ROWB);
    int rr = active ? row : 0;
    float4 a0 = ((const float4*)xp)[(size_t)rr * 2];
    float4 b0 = ((const float4*)xp)[(size_t)rr * 2 + 1];
    float xi0 = a0.x, xi1 = a0.y, xi2 = a0.z, xi3 = a0.w, xi4 = b0.x;
    float qi1 = b0.y + 1.0f;

    const float BIG = __uint_as_float(0x7F000000u);
    float best[8];
#pragma unroll
    for (int i = 0; i < 8; ++i) best[i] = BIG;

    unsigned jg0 = (unsigned)j0;
#pragma unroll 5
    for (int jj = 0; jj < SEGC; ++jj) {
        float4 a = xs4[jj];
        float2 b = xs2[jj];
        float dot = a.x * xi0;
        dot = fmaf(a.y, xi1, dot);
        dot = fmaf(a.z, xi2, dot);
        dot = fmaf(a.w, xi3, dot);
        dot = fmaf(b.x, xi4, dot);
        float d2 = fmaf(-2.0f, dot, b.y + qi1);      // d^2 + 1 >= ~1
        unsigned kb = (__float_as_uint(d2) & 0xFFFFF000u) | (jg0 + jj);
        float kf = __uint_as_float(kb);
        best[7] = med3f(best[6], best[7], kf);
        best[6] = med3f(best[5], best[6], kf);
        best[5] = med3f(best[4], best[5], kf);
        best[4] = med3f(best[3], best[4], kf);
        best[3] = med3f(best[2], best[3], kf);
        best[2] = med3f(best[1], best[2], kf);
        best[1] = med3f(best[0], best[1], kf);
        best[0] = fminf(best[0], kf);
    }
    if (active) {
        unsigned* o = partial + (((size_t)(nm * SSEGP + seg)) * HWT + row) * 8;
        uint4 lo = { __float_as_uint(best[0]), __float_as_uint(best[1]),
                     __float_as_uint(best[2]), __float_as_uint(best[3]) };
        uint4 hi = { __float_as_uint(best[4]), __float_as_uint(best[5]),
                     __float_as_uint(best[6]), __float_as_uint(best[7]) };
        ((uint4*)o)[0] = lo;
        ((uint4*)o)[1] = hi;
    }
}

// ================= fused kernels =================

// A: convert_a (928) + init Wcomb/Wbf0/g (1024) + knn_prep (113)
__global__ __launch_bounds__(256) void fusedA(const float* __restrict__ cnn,
                                              __hip_bfloat16* __restrict__ Abf,
                                              const float* __restrict__ Wg_rgb,
                                              const float* __restrict__ Wg_ir,
                                              float* __restrict__ Wcomb,
                                              float* __restrict__ g,
                                              __hip_bfloat16* __restrict__ Wbf,
                                              const float* __restrict__ rgb,
                                              const float* __restrict__ ir,
                                              float* __restrict__ xpack) {
    int bid = blockIdx.x;
    int t = threadIdx.x;
    if (bid < GEMM_BLKS) {
        __shared__ float st[64][65];
        int n = bid / 232;
        int rem = bid - n * 232;
        int k0 = (rem / 58) * 64;
        int m0 = (rem % 58) * 64;
        const float* src = cnn + (size_t)n * CH * HWT;
#pragma unroll
        for (int r = 0; r < 4; ++r) {
            int kl = r * 16 + (t >> 4);
            int ms = (t & 15) * 4;
            float4 v = {0.f, 0.f, 0.f, 0.f};
            if (m0 + ms < HWT) v = *(const float4*)(src + (size_t)(k0 + kl) * HWT + m0 + ms);
            st[ms + 0][kl] = v.x; st[ms + 1][kl] = v.y;
            st[ms + 2][kl] = v.z; st[ms + 3][kl] = v.w;
        }
        __syncthreads();
        int m = t >> 2, kg = (t & 3) * 16;
        union { uint4 u[2]; __hip_bfloat16 h[16]; } pk;
#pragma unroll
        for (int i = 0; i < 16; ++i) pk.h[i] = __float2bfloat16(st[m][kg + i]);
        __hip_bfloat16* dst = Abf + ((size_t)n * MPAD + m0 + m) * CH + k0 + kg;
        ((uint4*)dst)[0] = pk.u[0];
        ((uint4*)dst)[1] = pk.u[1];
    } else if (bid < GEMM_BLKS + 1024) {
        int e = (bid - GEMM_BLKS) * 256 + t;   // < 262144
        int o = e >> 8, j = e & 255;
        float v;
        if (o < 256)      v = Wg_rgb[o * 512 + j] + Wg_rgb[o * 512 + 256 + j];
        else if (o < 512) v = Wg_rgb[(o - 256) * 512 + 256 + j];
        else if (o < 768) v = Wg_ir[(o - 512) * 512 + j] + Wg_ir[(o - 512) * 512 + 256 + j];
        else              v = Wg_ir[(o - 768) * 512 + 256 + j];
        Wcomb[e] = v;
        __hip_bfloat16 h = __float2bfloat16(v);   // iter0: g == 1
#pragma unroll
        for (int n = 0; n < NB; ++n) Wbf[(size_t)n * 262144 + e] = h;
        if (e < NB * CH) g[e] = 1.0f;
    } else {
        int e = (bid - GEMM_BLKS - 1024) * 256 + t;
        if (e < 2 * NB * HWT) {
            int nm = e / HWT, j = e - nm * HWT;
            int mod = nm / NB, n = nm - mod * NB;
            const float* x = (mod == 0 ? rgb : ir) + (size_t)n * 5 * HWT;
            float v[5], q = 0.f;
#pragma unroll
            for (int d = 0; d < 5; ++d) { v[d] = x[d * HWT + j]; q = fmaf(v[d], v[d], q); }
            float* o = xpack + (size_t)e * 8;
#pragma unroll
            for (int d = 0; d < 5; ++d) o[d] = v[d];
            o[5] = q; o[6] = 0.f; o[7] = 0.f;
        }
    }
}

// B: gemm iter0 (even bids) interleaved with knn_main (odd bids + tail)
__global__ __launch_bounds__(256) void fusedB(const __hip_bfloat16* __restrict__ Abf,
                                              const __hip_bfloat16* __restrict__ Wbf,
                                              __hip_bfloat16* __restrict__ Yall,
                                              const float* __restrict__ xpack,
                                              unsigned* __restrict__ partial) {
    __shared__ char smem[32768];
    int bid = blockIdx.x;
    if (((bid & 1) == 0) && bid < 2 * GEMM_BLKS) {
        int gid = bid >> 1;
        gemm_body(gid % 232, gid / 232, Abf, Wbf, Yall, smem);
    } else {
        int kid = (bid < 2 * GEMM_BLKS) ? (bid >> 1) : (GEMM_BLKS + bid - 2 * GEMM_BLKS);
        knn_body(kid, xpack, partial, smem);
    }
}

// merge (450 blocks) + zero ccsum (8 blocks)
__global__ __launch_bounds__(256) void knn_merge_zero(const unsigned* __restrict__ partial,
                                                      int* __restrict__ knn_rgb,
                                                      int* __restrict__ knn_ir,
                                                      float* __restrict__ ccsum) {
    int bid = blockIdx.x;
    if (bid >= 450) {
        int e = (bid - 450) * 256 + threadIdx.x;
        if (e < NB * 512) ccsum[e] = 0.f;
        return;
    }
    int tid = bid * 256 + threadIdx.x;     // < 115200
    int rid = tid >> 1, sub = tid & 1;
    int nm = rid / HWT, row = rid - nm * HWT;
    const float BIG = __uint_as_float(0x7F000000u);
    float best[8];
#pragma unroll
    for (int i = 0; i < 8; ++i) best[i] = BIG;
    for (int s = sub; s < SSEGP; s += 2) {
        const unsigned* p = partial + (((size_t)(nm * SSEGP + s)) * HWT + row) * 8;
#pragma unroll
        for (int w = 0; w < 2; ++w) {
            uint4 v = ((const uint4*)p)[w];
            unsigned vv[4] = { v.x, v.y, v.z, v.w };
#pragma unroll
            for (int e = 0; e < 4; ++e) {
                float kf = __uint_as_float(vv[e]);
                best[7] = med3f(best[6], best[7], kf);
                best[6] = med3f(best[5], best[6], kf);
                best[5] = med3f(best[4], best[5], kf);
                best[4] = med3f(best[3], best[4], kf);
                best[3] = med3f(best[2], best[3], kf);
                best[2] = med3f(best[1], best[2], kf);
                best[1] = med3f(best[0], best[1], kf);
                best[0] = fminf(best[0], kf);
            }
        }
    }
    float other[8];
#pragma unroll
    for (int i = 0; i < 8; ++i) other[i] = __shfl_xor(best[i], 1);
#pragma unroll
    for (int i = 0; i < 8; ++i) {
        float kf = other[i];
        best[7] = med3f(best[6], best[7], kf);
        best[6] = med3f(best[5], best[6], kf);
        best[5] = med3f(best[4], best[5], kf);
        best[4] = med3f(best[3], best[4], kf);
        best[3] = med3f(best[2], best[3], kf);
        best[2] = med3f(best[1], best[2], kf);
        best[1] = med3f(best[0], best[1], kf);
        best[0] = fminf(best[0], kf);
    }
    if (sub == 0) {
        int mod = nm / NB, n = nm - mod * NB;
        int* o = (mod == 0 ? knn_rgb : knn_ir) + ((size_t)n * HWT + row) * KNN;
#pragma unroll
        for (int i = 0; i < 8; ++i) o[i] = (int)(__float_as_uint(best[i]) & 0xFFFu);
    }
}

// scale_w (512 blocks) + zero ccsum (8 blocks) for iter 1
__global__ __launch_bounds__(256) void scale_w_zero(const float* __restrict__ Wcomb,
                                                    const float* __restrict__ g,
                                                    __hip_bfloat16* __restrict__ Wbf,
                                                    float* __restrict__ ccsum) {
    int bid = blockIdx.x;
    if (bid >= 512) {
        int e = (bid - 512) * 256 + threadIdx.x;
        if (e < NB * 512) ccsum[e] = 0.f;
        return;
    }
    int n = bid >> 7;
    int gid = (bid & 127) * 256 + threadIdx.x;
    int o = gid >> 5;
    int kb = (gid & 31) * 8;
    const float* w = Wcomb + o * 256 + kb;
    const float* gp = g + n * CH + kb;
    union { uint4 u; __hip_bfloat16 h[8]; } pk;
#pragma unroll
    for (int i = 0; i < 8; ++i) pk.h[i] = __float2bfloat16(w[i] * gp[i]);
    *(uint4*)(Wbf + ((size_t)n * 1024 + o) * CH + kb) = pk.u;
}

__global__ __launch_bounds__(256) void gemm_k(const __hip_bfloat16* __restrict__ Abf,
                                              const __hip_bfloat16* __restrict__ Wbf,
                                              __hip_bfloat16* __restrict__ Yall) {
    __shared__ char smem[32768];
    int gid = blockIdx.x;
    gemm_body(gid % 232, gid / 232, Abf, Wbf, Yall, smem);
}

// ================= gather / SE / final =================

__global__ __launch_bounds__(256) void gather_kernel(const __hip_bfloat16* __restrict__ Yall,
                                                     const int* __restrict__ knn_rgb,
                                                     const int* __restrict__ knn_ir,
                                                     const float* __restrict__ b_rgb,
                                                     const float* __restrict__ b_ir,
                                                     float* __restrict__ ccsum) {
    int lid = blockIdx.x;                 // 0..899
    int xcd = lid & 7, sub = lid >> 3;    // 900 = 8*112 + 4 -> q=112, r=4
    int wg = (xcd < 4 ? xcd * 113 : 4 * 113 + (xcd - 4) * 112) + sub;
    int n = wg / 225;
    int hwbase = (wg - n * 225) * POSB;
    int t = threadIdx.x;
    int half = t >> 7;
    int cp = (t & 127) << 1;
    __shared__ int sidx[POSB][2][KNN];
    {
        int p = t >> 4, rem = t & 15;
        int hw = hwbase + p;
        int v;
        if (rem < 8) v = knn_rgb[((size_t)n * HWT + hw) * KNN + rem];
        else         v = knn_ir[((size_t)n * HWT + hw) * KNN + (rem - 8)];
        sidx[p][rem >> 3][rem & 7] = v;
    }
    __syncthreads();
    const float* bias = half ? b_ir : b_rgb;
    float b0 = bias[cp], b1 = bias[cp + 1];
    float acc0 = 0.f, acc1 = 0.f;
    const __hip_bfloat16* Y = Yall + (size_t)n * HWT * 1024;
    int offA = half * 512 + cp;
    int offB = half * 512 + 256 + cp;
    for (int p = 0; p < POSB; ++p) {
        float m0 = 0.f, m1 = 0.f;
#pragma unroll
        for (int k = 0; k < KNN; ++k) {
            int jA = sidx[p][half][k];
            int jB = sidx[p][half ^ 1][k];
            unsigned u1 = *(const unsigned*)(Y + (size_t)jA * 1024 + offA);
            unsigned u2 = *(const unsigned*)(Y + (size_t)jB * 1024 + offB);
            float a0 = __uint_as_float(u1 << 16);
            float a1 = __uint_as_float(u1 & 0xFFFF0000u);
            float c0 = __uint_as_float(u2 << 16);
            float c1 = __uint_as_float(u2 & 0xFFFF0000u);
            m0 = fmaxf(m0, a0 - c0 + b0);
            m1 = fmaxf(m1, a1 - c1 + b1);
        }
        acc0 += m0;
        acc1 += m1;
    }
    atomicAdd(&ccsum[n * 512 + half * 256 + cp], acc0);
    atomicAdd(&ccsum[n * 512 + half * 256 + cp + 1], acc1);
}

__global__ __launch_bounds__(256) void se_kernel(const float* __restrict__ ccsum,
                                                 const float* __restrict__ W1,
                                                 const float* __restrict__ b1,
                                                 const float* __restrict__ W2,
                                                 const float* __restrict__ b2,
                                                 float* __restrict__ g) {
    int n = blockIdx.x;
    int t = threadIdx.x;
    __shared__ float hid[16];
    __shared__ float cc[512];
    cc[t] = ccsum[n * 512 + t] * (1.0f / HWT);
    cc[256 + t] = ccsum[n * 512 + 256 + t] * (1.0f / HWT);
    __syncthreads();
    if (t < 16) {
        float s = b1[t];
        for (int j = 0; j < 512; ++j) s = fmaf(W1[t * 512 + j], cc[j], s);
        hid[t] = fmaxf(s, 0.f);
    }
    __syncthreads();
    float s = b2[t];
#pragma unroll
    for (int q = 0; q < 16; ++q) s = fmaf(W2[t * 16 + q], hid[q], s);
    float se = 1.0f / (1.0f + expf(-s));
    g[n * CH + t] *= se;
}

__global__ void final_kernel(const float* __restrict__ cnn, const float* __restrict__ g,
                             const float* __restrict__ gamma, float* __restrict__ out) {
    int t = blockIdx.x * blockDim.x + threadIdx.x;
    if (t >= NB * CH * HWT / 4) return;
    int nc = (t * 4) / HWT;
    float4 x = ((const float4*)cnn)[t];
    float s = gamma[0] * g[nc] + 1.0f;
    float4 o;
    o.x = fmaxf(s * x.x, 0.f);
    o.y = fmaxf(s * x.y, 0.f);
    o.z = fmaxf(s * x.z, 0.f);
    o.w = fmaxf(s * x.w, 0.f);
    ((float4*)out)[t] = o;
}

extern "C" void kernel_launch(void* const* d_in, const int* in_sizes, int n_in,
                              void* d_out, int out_size, void* d_ws, size_t ws_size,
                              hipStream_t stream) {
    const float* cnn    = (const float*)d_in[0];
    const float* rgb    = (const float*)d_in[1];
    const float* ir     = (const float*)d_in[2];
    const float* Wg_rgb = (const float*)d_in[3];
    const float* bg_rgb = (const float*)d_in[4];
    const float* Wg_ir  = (const float*)d_in[5];
    const float* bg_ir  = (const float*)d_in[6];
    const float* Wse1   = (const float*)d_in[7];
    const float* bse1   = (const float*)d_in[8];
    const float* Wse2   = (const float*)d_in[9];
    const float* bse2   = (const float*)d_in[10];
    const float* gamma  = (const float*)d_in[11];
    float* out = (float*)d_out;

    char* ws = (char*)d_ws;
    size_t off = 0;
    float* xpack = (float*)(ws + off); off += (size_t)2 * NB * HWT * 8 * 4;     // 0.92 MB
    int* knn_rgb = (int*)(ws + off); off += (size_t)NB * HWT * KNN * 4;
    int* knn_ir  = (int*)(ws + off); off += (size_t)NB * HWT * KNN * 4;
    float* Wcomb = (float*)(ws + off); off += (size_t)1024 * 256 * 4;
    __hip_bfloat16* Wbf = (__hip_bfloat16*)(ws + off); off += (size_t)NB * 1024 * CH * 2;
    __hip_bfloat16* Abf = (__hip_bfloat16*)(ws + off); off += (size_t)NB * MPAD * CH * 2;
    __hip_bfloat16* Yall = (__hip_bfloat16*)(ws + off); off += (size_t)NB * HWT * 1024 * 2;
    unsigned* partial = (unsigned*)(ws + off);
    off += (size_t)2 * NB * SSEGP * HWT * 8 * 4;                                // 7.37 MB (no alias: concurrent with Y)
    float* ccsum = (float*)(ws + off); off += (size_t)NB * 512 * 4;
    float* g     = (float*)(ws + off); off += (size_t)NB * CH * 4;
    // total ~49.5 MB

    // prolog: convert_a + Wcomb/Wbf(it0)/g + knn_prep, all independent
    fusedA<<<GEMM_BLKS + 1024 + 113, 256, 0, stream>>>(cnn, Abf, Wg_rgb, Wg_ir, Wcomb, g,
                                                       Wbf, rgb, ir, xpack);
    // iter 0: gemm (hidden) || knn_main
    fusedB<<<B_BLKS, 256, 0, stream>>>(Abf, Wbf, Yall, xpack, partial);
    knn_merge_zero<<<458, 256, 0, stream>>>(partial, knn_rgb, knn_ir, ccsum);
    gather_kernel<<<900, 256, 0, stream>>>(Yall, knn_rgb, knn_ir, bg_rgb, bg_ir, ccsum);
    se_kernel<<<NB, 256, 0, stream>>>(ccsum, Wse1, bse1, Wse2, bse2, g);
    // iter 1
    scale_w_zero<<<520, 256, 0, stream>>>(Wcomb, g, Wbf, ccsum);
    gemm_k<<<GEMM_BLKS, 256, 0, stream>>>(Abf, Wbf, Yall);
    gather_kernel<<<900, 256, 0, stream>>>(Yall, knn_rgb, knn_ir, bg_rgb, bg_ir, ccsum);
    se_kernel<<<NB, 256, 0, stream>>>(ccsum, Wse1, bse1, Wse2, bse2, g);
    final_kernel<<<3600, 256, 0, stream>>>(cnn, g, gamma, out);
}